// Round 2
// baseline (4031.105 us; speedup 1.0000x reference)
//
#include <hip/hip_runtime.h>
#include <hip/hip_bf16.h>
#include <math.h>

// Problem constants
#define B_ 4
#define VH_ 130
#define VL_ 120
#define EP_ 256
#define R_ 506           // VH+VL+EP
#define DIN_ 256
#define DEP_ 128
#define D_ 512
#define H_ 16
#define NL_ 8
#define HID_ 2048

#define MODE_STORE 0
#define MODE_ADD_BIAS 1   // C += acc + bias[n] (bias may be null -> 0)
#define MODE_SWIGLU 2     // C = silu(C_old) * acc

// ---------------------------------------------------------------------------
// Generic tiled fp32 GEMM: C[m,n] (+)= sum_k A[m,k] * W[n,k]
// A: logical M x K, row stride K, with row remap (rpb/R/base)
// W: N x K row-major (weights, transposed multiply)
// C: row stride N, with row remap
// ---------------------------------------------------------------------------
__global__ __launch_bounds__(256) void gemm_kernel(
    const float* __restrict__ A, const float* __restrict__ W,
    float* __restrict__ C, const float* __restrict__ bias,
    int M, int N, int K,
    int A_rpb, int A_R, int A_base,
    int C_rpb, int C_R, int C_base,
    int mode) {
  __shared__ __align__(16) float As[16][68];
  __shared__ __align__(16) float Bs[16][68];

  const int t = threadIdx.x;
  const int bm = blockIdx.y, bn = blockIdx.x;
  const int ty = t >> 4, tx = t & 15;

  // loader mapping: each thread loads one float4 of A and one of W per k-step
  const int lr = t >> 2;           // 0..63 tile row
  const int c0 = (t & 3) * 4;      // 0,4,8,12 k-offset

  const int ma = bm * 64 + lr;
  const bool va = (ma < M);
  int ar = 0;
  if (va) ar = (ma / A_rpb) * A_R + A_base + (ma % A_rpb);
  const float* pA = A + (size_t)ar * K + c0;

  const int nw = bn * 64 + lr;
  const bool vw = (nw < N);
  const float* pW = W + (size_t)nw * K + c0;

  float acc[4][4];
#pragma unroll
  for (int i = 0; i < 4; i++)
#pragma unroll
    for (int j = 0; j < 4; j++) acc[i][j] = 0.f;

  for (int k0 = 0; k0 < K; k0 += 16) {
    __syncthreads();
    float4 avv = va ? *(const float4*)(pA + k0) : make_float4(0.f, 0.f, 0.f, 0.f);
    float4 wvv = vw ? *(const float4*)(pW + k0) : make_float4(0.f, 0.f, 0.f, 0.f);
    As[c0 + 0][lr] = avv.x; As[c0 + 1][lr] = avv.y;
    As[c0 + 2][lr] = avv.z; As[c0 + 3][lr] = avv.w;
    Bs[c0 + 0][lr] = wvv.x; Bs[c0 + 1][lr] = wvv.y;
    Bs[c0 + 2][lr] = wvv.z; Bs[c0 + 3][lr] = wvv.w;
    __syncthreads();
#pragma unroll
    for (int kk = 0; kk < 16; kk++) {
      float4 a = *(const float4*)&As[kk][ty * 4];
      float4 bv = *(const float4*)&Bs[kk][tx * 4];
      float av[4] = {a.x, a.y, a.z, a.w};
      float bb[4] = {bv.x, bv.y, bv.z, bv.w};
#pragma unroll
      for (int i = 0; i < 4; i++)
#pragma unroll
        for (int j = 0; j < 4; j++) acc[i][j] += av[i] * bb[j];
    }
  }

  const int m0 = bm * 64 + ty * 4;
  const int n0 = bn * 64 + tx * 4;
#pragma unroll
  for (int i = 0; i < 4; i++) {
    int m = m0 + i;
    if (m >= M) continue;
    int crow = (m / C_rpb) * C_R + C_base + (m % C_rpb);
    float* cp = C + (size_t)crow * N;
#pragma unroll
    for (int j = 0; j < 4; j++) {
      int n = n0 + j;
      if (n >= N) continue;
      float r = acc[i][j];
      if (mode == MODE_STORE) {
        cp[n] = r;
      } else if (mode == MODE_ADD_BIAS) {
        float bb = bias ? bias[n] : 0.f;
        cp[n] = cp[n] + r + bb;
      } else {  // MODE_SWIGLU: C = silu(old) * acc
        float old = cp[n];
        cp[n] = (old / (1.f + expf(-old))) * r;
      }
    }
  }
}

// ---------------------------------------------------------------------------
// LayerNorm: one block per row of 512
// ---------------------------------------------------------------------------
__global__ __launch_bounds__(256) void ln_kernel(
    const float* __restrict__ x, const float* __restrict__ g,
    const float* __restrict__ b, float* __restrict__ out) {
  const int row = blockIdx.x;
  const int t = threadIdx.x;
  const float* xr = x + (size_t)row * D_;
  float v0 = xr[t], v1 = xr[t + 256];
  float s = v0 + v1, s2 = v0 * v0 + v1 * v1;
#pragma unroll
  for (int o = 32; o > 0; o >>= 1) {
    s += __shfl_down(s, o);
    s2 += __shfl_down(s2, o);
  }
  __shared__ float w1[4], w2[4], mv[2];
  const int w = t >> 6;
  if ((t & 63) == 0) { w1[w] = s; w2[w] = s2; }
  __syncthreads();
  if (t == 0) {
    float ss = w1[0] + w1[1] + w1[2] + w1[3];
    float ss2 = w2[0] + w2[1] + w2[2] + w2[3];
    float mean = ss * (1.f / D_);
    float var = ss2 * (1.f / D_) - mean * mean;
    mv[0] = mean;
    mv[1] = rsqrtf(var + 1e-5f);
  }
  __syncthreads();
  float mean = mv[0], inv = mv[1];
  float* orow = out + (size_t)row * D_;
  orow[t] = (v0 - mean) * inv * g[t] + b[t];
  orow[t + 256] = (v1 - mean) * inv * g[t + 256] + b[t + 256];
}

// ---------------------------------------------------------------------------
// Concat rots/trans/mask into contiguous (B,R,...) buffers
// ---------------------------------------------------------------------------
__global__ void concat_kernel(
    const float* __restrict__ vh_rots, const float* __restrict__ vh_trans,
    const float* __restrict__ vl_rots, const float* __restrict__ vl_trans,
    const float* __restrict__ ep_rots, const float* __restrict__ ep_trans,
    const int* __restrict__ vh_mask, const int* __restrict__ vl_mask,
    const int* __restrict__ ep_mask,
    float* __restrict__ rots, float* __restrict__ trans, int* __restrict__ mask) {
  int idx = blockIdx.x * blockDim.x + threadIdx.x;
  if (idx >= B_ * R_) return;
  int b = idx / R_, r = idx % R_;
  const float* sr; const float* st; int sm;
  if (r < VH_) {
    sr = vh_rots + (size_t)(b * VH_ + r) * 9;
    st = vh_trans + (size_t)(b * VH_ + r) * 3;
    sm = vh_mask[b * VH_ + r];
  } else if (r < VH_ + VL_) {
    int rr = r - VH_;
    sr = vl_rots + (size_t)(b * VL_ + rr) * 9;
    st = vl_trans + (size_t)(b * VL_ + rr) * 3;
    sm = vl_mask[b * VL_ + rr];
  } else {
    int rr = r - VH_ - VL_;
    sr = ep_rots + (size_t)(b * EP_ + rr) * 9;
    st = ep_trans + (size_t)(b * EP_ + rr) * 3;
    sm = ep_mask[b * EP_ + rr];
  }
#pragma unroll
  for (int k = 0; k < 9; k++) rots[(size_t)idx * 9 + k] = sr[k];
#pragma unroll
  for (int k = 0; k < 3; k++) trans[(size_t)idx * 3 + k] = st[k];
  mask[idx] = sm;
}

// ---------------------------------------------------------------------------
// Positional encoding add for vh (pos=r) and vl (pos=r-VH) rows
// ---------------------------------------------------------------------------
__global__ void pe_kernel(float* __restrict__ emb) {
  int idx = blockIdx.x * blockDim.x + threadIdx.x;
  const int total = B_ * (VH_ + VL_) * D_;
  if (idx >= total) return;
  int d = idx & (D_ - 1);
  int rb = idx >> 9;
  int r = rb % (VH_ + VL_);
  int b = rb / (VH_ + VL_);
  float pos = (r < VH_) ? (float)r : (float)(r - VH_);
  // ang = pos * 1000^(-2d/511)
  float ang = pos * expf((float)d * (-2.0f / 511.0f) * 6.907755278982137f);
  float enc = (d & 1) ? cosf(ang) : sinf(ang);
  emb[((size_t)b * R_ + r) * D_ + d] += enc;
}

// ---------------------------------------------------------------------------
// Rotate QKV fields by per-residue rotation; add trans to point fields
// qkv_raw row layout: [f(5)][h(16)][d(3)]
// ---------------------------------------------------------------------------
__global__ __launch_bounds__(128) void rotate_kernel(
    const float* __restrict__ qkv_raw, const float* __restrict__ rots,
    const float* __restrict__ trans, float* __restrict__ Qr,
    float* __restrict__ Kr, float* __restrict__ Pq, float* __restrict__ Pk,
    float* __restrict__ V) {
  const int row = blockIdx.x;
  const int t = threadIdx.x;
  __shared__ float Rm[9], tr[3], raw[240];
  if (t < 9) Rm[t] = rots[(size_t)row * 9 + t];
  if (t >= 9 && t < 12) tr[t - 9] = trans[(size_t)row * 3 + (t - 9)];
  for (int i = t; i < 240; i += 128) raw[i] = qkv_raw[(size_t)row * 240 + i];
  __syncthreads();
  if (t < 80) {
    int f = t / 16, h = t % 16;
    float x = raw[f * 48 + h * 3 + 0];
    float y = raw[f * 48 + h * 3 + 1];
    float z = raw[f * 48 + h * 3 + 2];
    float r0 = Rm[0] * x + Rm[1] * y + Rm[2] * z;
    float r1 = Rm[3] * x + Rm[4] * y + Rm[5] * z;
    float r2 = Rm[6] * x + Rm[7] * y + Rm[8] * z;
    if (f == 2 || f == 3) { r0 += tr[0]; r1 += tr[1]; r2 += tr[2]; }
    float* dst;
    if (f == 0) dst = Qr;
    else if (f == 1) dst = Kr;
    else if (f == 2) dst = Pq;
    else if (f == 3) dst = Pk;
    else dst = V;
    size_t o = (size_t)row * 48 + h * 3;
    dst[o] = r0; dst[o + 1] = r1; dst[o + 2] = r2;
  }
}

// ---------------------------------------------------------------------------
// Fused attention per (b, i): logits + softmax over j + PV + inverse rotation
// ---------------------------------------------------------------------------
#define LSTR 517
__global__ __launch_bounds__(256) void attn_kernel(
    const float* __restrict__ Qr, const float* __restrict__ Kr,
    const float* __restrict__ Pq, const float* __restrict__ Pk,
    const float* __restrict__ Vv, const float* __restrict__ rots,
    const int* __restrict__ mask, const float* __restrict__ rs,
    const float* __restrict__ ds, float* __restrict__ o) {
  const int blk = blockIdx.x;
  const int b = blk / R_;
  const int i = blk % R_;
  const int t = threadIdx.x;

  __shared__ float L[16 * LSTR];
  __shared__ float qri[48], pqi[48], cr[16], cd[16];
  __shared__ float red[256], red2[256];
  __shared__ float maxv[16], sumv[16];
  __shared__ float og[48], P[192];

  const size_t rowbase = (size_t)(b * R_) * 48;
  if (t < 48) {
    qri[t] = Qr[(size_t)blk * 48 + t];
    pqi[t] = Pq[(size_t)blk * 48 + t];
  } else if (t < 64) {
    int h = t - 48;
    const float sc = 0.5773502691896258f;
    cr[h] = log1pf(expf(rs[h])) * sc;
    cd[h] = log1pf(expf(ds[h])) * sc;
  }
  __syncthreads();

  const int mi = mask[b * R_ + i];
  for (int j = t; j < R_; j += 256) {
    int mj = mask[b * R_ + j];
    float bias = (mi | mj) ? -1e9f : 0.0f;
    const float* kr = Kr + rowbase + (size_t)j * 48;
    const float* pk = Pk + rowbase + (size_t)j * 48;
#pragma unroll
    for (int h = 0; h < 16; h++) {
      float ar = qri[h * 3] * kr[h * 3] + qri[h * 3 + 1] * kr[h * 3 + 1] +
                 qri[h * 3 + 2] * kr[h * 3 + 2];
      float dx = pqi[h * 3] - pk[h * 3];
      float dy = pqi[h * 3 + 1] - pk[h * 3 + 1];
      float dz = pqi[h * 3 + 2] - pk[h * 3 + 2];
      float dist = sqrtf(dx * dx + dy * dy + dz * dz);
      L[h * LSTR + j] = ar * cr[h] - dist * cd[h] + bias;
    }
  }
  __syncthreads();

  // per-head max
  const int h = t >> 4, g = t & 15;
  float m = -3e38f;
  for (int j = g; j < R_; j += 16) m = fmaxf(m, L[h * LSTR + j]);
  red[h * 16 + g] = m;
  __syncthreads();
  if (t < 16) {
    float mm = red[t * 16];
#pragma unroll
    for (int k = 1; k < 16; k++) mm = fmaxf(mm, red[t * 16 + k]);
    maxv[t] = mm;
  }
  __syncthreads();

  // exp and sum
  float s = 0.f;
  float mh = maxv[h];
  for (int j = g; j < R_; j += 16) {
    float e = expf(L[h * LSTR + j] - mh);
    L[h * LSTR + j] = e;
    s += e;
  }
  red2[h * 16 + g] = s;
  __syncthreads();
  if (t < 16) {
    float ss = 0.f;
#pragma unroll
    for (int k = 0; k < 16; k++) ss += red2[t * 16 + k];
    sumv[t] = ss;
  }
  __syncthreads();

  // PV: o_global[h][d] = sum_j A * V
  if (t < 192) {
    int idx = t >> 2, lane = t & 3;
    int hh = idx / 3, d = idx % 3;
    float acc = 0.f;
    for (int j = lane; j < R_; j += 4)
      acc += L[hh * LSTR + j] * Vv[rowbase + (size_t)j * 48 + hh * 3 + d];
    P[idx * 4 + lane] = acc;
  }
  __syncthreads();
  if (t < 48) {
    int hh = t / 3;
    og[t] = (P[t * 4] + P[t * 4 + 1] + P[t * 4 + 2] + P[t * 4 + 3]) / sumv[hh];
  }
  __syncthreads();
  // inverse rotation: out[h,i3] = sum_j rots[j,i3] * og[h,j]
  if (t < 48) {
    int hh = t / 3, i3 = t % 3;
    const float* Rm = rots + (size_t)blk * 9;
    float val = Rm[0 * 3 + i3] * og[hh * 3 + 0] +
                Rm[1 * 3 + i3] * og[hh * 3 + 1] +
                Rm[2 * 3 + i3] * og[hh * 3 + 2];
    o[(size_t)blk * 48 + t] = val;
  }
}

// ---------------------------------------------------------------------------
// Output head combine: out = mask ? x : x + t1 * sigmoid(t2 + gate_b)
// ---------------------------------------------------------------------------
__global__ void combine_kernel(
    const float* __restrict__ x, const float* __restrict__ t1,
    const float* __restrict__ t2, const float* __restrict__ gate_b,
    const int* __restrict__ mask, float* __restrict__ out, int total) {
  int idx = blockIdx.x * blockDim.x + threadIdx.x;
  if (idx >= total) return;
  int dm = idx & (DIN_ - 1);
  int row = idx >> 8;  // DIN_=256
  float xv = x[idx];
  if (mask[row]) {
    out[idx] = xv;
  } else {
    float gate = 1.f / (1.f + expf(-(t2[idx] + gate_b[dm])));
    out[idx] = xv + t1[idx] * gate;
  }
}

// ---------------------------------------------------------------------------
extern "C" void kernel_launch(void* const* d_in, const int* in_sizes, int n_in,
                              void* d_out, int out_size, void* d_ws, size_t ws_size,
                              hipStream_t stream) {
  const float* vh_x = (const float*)d_in[0];
  const float* vl_x = (const float*)d_in[1];
  const float* vh_rots = (const float*)d_in[2];
  const float* vh_trans = (const float*)d_in[3];
  const float* vl_rots = (const float*)d_in[4];
  const float* vl_trans = (const float*)d_in[5];
  const float* ep_feats = (const float*)d_in[6];
  const float* ep_rots = (const float*)d_in[7];
  const float* ep_trans = (const float*)d_in[8];
  const int* vh_mask = (const int*)d_in[9];
  const int* vl_mask = (const int*)d_in[10];
  const int* ep_mask = (const int*)d_in[11];
  const float* vh_emb_w = (const float*)d_in[12];
  const float* vl_emb_w = (const float*)d_in[13];
  const float* tgt_emb_w = (const float*)d_in[14];
  const float* qkv_w = (const float*)d_in[15];
  const float* out_w = (const float*)d_in[16];
  const float* out_b = (const float*)d_in[17];
  const float* ln_g = (const float*)d_in[18];
  const float* ln_b = (const float*)d_in[19];
  const float* r_scale = (const float*)d_in[20];
  const float* d_scale = (const float*)d_in[21];
  const float* ln2_g = (const float*)d_in[22];
  const float* ln2_b = (const float*)d_in[23];
  const float* w12 = (const float*)d_in[24];
  const float* w3 = (const float*)d_in[25];
  const float* out_vh_w = (const float*)d_in[26];
  const float* out_vh_gate_w = (const float*)d_in[27];
  const float* out_vh_gate_b = (const float*)d_in[28];
  const float* out_vl_w = (const float*)d_in[29];
  const float* out_vl_gate_w = (const float*)d_in[30];
  const float* out_vl_gate_b = (const float*)d_in[31];

  const int BR = B_ * R_;  // 2024

  // workspace layout (floats)
  float* ws = (float*)d_ws;
  float* emb = ws;                           // 2024*512 = 1,036,288
  float* xn = emb + (size_t)BR * D_;         // 1,036,288
  float* qkvr = xn + (size_t)BR * D_;        // 2024*240 = 485,760
  float* Qr = qkvr + (size_t)BR * 240;       // 2024*48 = 97,152
  float* Kr = Qr + (size_t)BR * 48;
  float* Pq = Kr + (size_t)BR * 48;
  float* Pk = Pq + (size_t)BR * 48;
  float* Vv = Pk + (size_t)BR * 48;
  float* ob = Vv + (size_t)BR * 48;          // 97,152
  float* gbuf = ob + (size_t)BR * 48;        // 2024*2048 = 4,145,152
  float* rots_c = gbuf + (size_t)BR * HID_;  // 18,216
  float* trans_c = rots_c + (size_t)BR * 9;  // 6,072
  int* mask_c = (int*)(trans_c + (size_t)BR * 3);  // 2024 ints
  float* t1 = (float*)(mask_c + BR);         // 133,120
  float* t2 = t1 + 133120;                   // 133,120

  auto gemm = [&](const float* A, const float* W, float* C, const float* bias,
                  int M, int N, int K, int Arpb, int AR, int Abase, int Crpb,
                  int CR, int Cbase, int mode) {
    dim3 g((N + 63) / 64, (M + 63) / 64);
    gemm_kernel<<<g, 256, 0, stream>>>(A, W, C, bias, M, N, K, Arpb, AR, Abase,
                                       Crpb, CR, Cbase, mode);
  };

  // concat rots/trans/mask
  concat_kernel<<<(BR + 255) / 256, 256, 0, stream>>>(
      vh_rots, vh_trans, vl_rots, vl_trans, ep_rots, ep_trans, vh_mask,
      vl_mask, ep_mask, rots_c, trans_c, mask_c);

  // embeddings into emb (row-remapped)
  gemm(vh_x, vh_emb_w, emb, nullptr, B_ * VH_, D_, DIN_, B_ * VH_, B_ * VH_, 0,
       VH_, R_, 0, MODE_STORE);
  gemm(vl_x, vl_emb_w, emb, nullptr, B_ * VL_, D_, DIN_, B_ * VL_, B_ * VL_, 0,
       VL_, R_, VH_, MODE_STORE);
  gemm(ep_feats, tgt_emb_w, emb, nullptr, B_ * EP_, D_, DEP_, B_ * EP_,
       B_ * EP_, 0, EP_, R_, VH_ + VL_, MODE_STORE);
  {
    int total = B_ * (VH_ + VL_) * D_;
    pe_kernel<<<(total + 255) / 256, 256, 0, stream>>>(emb);
  }

  for (int l = 0; l < NL_; l++) {
    const float* qw = qkv_w + (size_t)l * 240 * D_;
    const float* ow = out_w + (size_t)l * D_ * 48;
    const float* obias = out_b + (size_t)l * D_;
    const float* lg = ln_g + (size_t)l * D_;
    const float* lb = ln_b + (size_t)l * D_;
    const float* l2g = ln2_g + (size_t)l * D_;
    const float* l2b = ln2_b + (size_t)l * D_;
    const float* rs = r_scale + (size_t)l * H_;
    const float* dsc = d_scale + (size_t)l * H_;
    const float* w12a = w12 + (size_t)l * 2 * HID_ * D_;
    const float* w12b = w12a + (size_t)HID_ * D_;
    const float* w3l = w3 + (size_t)l * D_ * HID_;

    // attention
    ln_kernel<<<BR, 256, 0, stream>>>(emb, lg, lb, xn);
    gemm(xn, qw, qkvr, nullptr, BR, 240, D_, BR, BR, 0, BR, BR, 0, MODE_STORE);
    rotate_kernel<<<BR, 128, 0, stream>>>(qkvr, rots_c, trans_c, Qr, Kr, Pq,
                                          Pk, Vv);
    attn_kernel<<<BR, 256, 0, stream>>>(Qr, Kr, Pq, Pk, Vv, rots_c, mask_c, rs,
                                        dsc, ob);
    gemm(ob, ow, emb, obias, BR, D_, 48, BR, BR, 0, BR, BR, 0, MODE_ADD_BIAS);

    // swiglu
    ln_kernel<<<BR, 256, 0, stream>>>(emb, l2g, l2b, xn);
    gemm(xn, w12a, gbuf, nullptr, BR, HID_, D_, BR, BR, 0, BR, BR, 0,
         MODE_STORE);
    gemm(xn, w12b, gbuf, nullptr, BR, HID_, D_, BR, BR, 0, BR, BR, 0,
         MODE_SWIGLU);
    gemm(gbuf, w3l, emb, nullptr, BR, D_, HID_, BR, BR, 0, BR, BR, 0,
         MODE_ADD_BIAS);
  }

  // output heads
  // vh
  gemm(emb, out_vh_w, t1, nullptr, B_ * VH_, DIN_, D_, VH_, R_, 0, B_ * VH_,
       B_ * VH_, 0, MODE_STORE);
  gemm(emb, out_vh_gate_w, t2, nullptr, B_ * VH_, DIN_, D_, VH_, R_, 0,
       B_ * VH_, B_ * VH_, 0, MODE_STORE);
  {
    int total = B_ * VH_ * DIN_;
    combine_kernel<<<(total + 255) / 256, 256, 0, stream>>>(
        vh_x, t1, t2, out_vh_gate_b, vh_mask, (float*)d_out, total);
  }
  // vl
  gemm(emb, out_vl_w, t1, nullptr, B_ * VL_, DIN_, D_, VL_, R_, VH_, B_ * VL_,
       B_ * VL_, 0, MODE_STORE);
  gemm(emb, out_vl_gate_w, t2, nullptr, B_ * VL_, DIN_, D_, VL_, R_, VH_,
       B_ * VL_, B_ * VL_, 0, MODE_STORE);
  {
    int total = B_ * VL_ * DIN_;
    combine_kernel<<<(total + 255) / 256, 256, 0, stream>>>(
        vl_x, t1, t2, out_vl_gate_b, vl_mask,
        (float*)d_out + (size_t)B_ * VH_ * DIN_, total);
  }
}

// Round 3
// 1757.047 us; speedup vs baseline: 2.2942x; 2.2942x over previous
//
#include <hip/hip_runtime.h>
#include <hip/hip_bf16.h>
#include <math.h>
#include <stdint.h>

// Problem constants
#define B_ 4
#define VH_ 130
#define VL_ 120
#define EP_ 256
#define R_ 506           // VH+VL+EP
#define RP_ 512          // padded R for transposed K/V layouts
#define DIN_ 256
#define DEP_ 128
#define D_ 512
#define H_ 16
#define NL_ 8
#define HID_ 2048

#define MODE_STORE 0
#define MODE_ADD_BIAS 1
#define MODE_SWIGLU16 2   // Ch = f16(silu(aux) * acc)

typedef _Float16 half8 __attribute__((ext_vector_type(8)));
typedef float f32x4 __attribute__((ext_vector_type(4)));

// async global->LDS 16B copy (guide §5: width must be literal)
#define ASYNC16(ldsdst, gsrc)                                                  \
  __builtin_amdgcn_global_load_lds(                                            \
      (const __attribute__((address_space(1))) unsigned int*)(gsrc),           \
      (__attribute__((address_space(3))) unsigned int*)(ldsdst), 16, 0, 0)

// ---------------------------------------------------------------------------
// fp16 MFMA GEMM: C[m,n] (+)= sum_k A[m,k] * W[n,k]
// A: M x K f16 row-major; W: N x K f16 row-major. BM=128 BN=64 BK=32.
// 256 threads = 4 waves in 2x2 (each wave 64x32). Chunked-K LDS layout:
// slot (c, row) at offset (c*ROWS + row)*8 halfs -> frag reads are dense.
// ---------------------------------------------------------------------------
__global__ __launch_bounds__(256) void gemm16_kernel(
    const _Float16* __restrict__ A, const _Float16* __restrict__ W,
    float* __restrict__ C, const float* __restrict__ bias,
    const float* __restrict__ aux, _Float16* __restrict__ Ch,
    int M, int N, int K, int mode) {
  __shared__ _Float16 Al[2][4096];  // [buf][(c*128+row)*8], 128 rows x 32 k
  __shared__ _Float16 Bl[2][2048];  // [buf][(c*64+col)*8],   64 cols x 32 k

  const int t = threadIdx.x;
  const int bm = blockIdx.y, bn = blockIdx.x;
  const int lane = t & 63;
  const int w = t >> 6;
  const int wm = w >> 1, wn = w & 1;

  // staging source pointers (pre-swizzled global sources, linear LDS dest)
  // A slots: s = t (c=t>>7, r=t&127) and s = t+256 (c=2+(t>>7))
  int r_ = t & 127;
  int gr = bm * 128 + r_;
  if (gr >= M) gr = M - 1;
  const _Float16* pA0 = A + (size_t)gr * K + (t >> 7) * 8;
  const _Float16* pA1 = A + (size_t)gr * K + (2 + (t >> 7)) * 8;
  int col_ = t & 63;
  int gc = bn * 64 + col_;
  if (gc >= N) gc = N - 1;
  const _Float16* pB = W + (size_t)gc * K + (t >> 6) * 8;

  f32x4 acc[4][2];
#pragma unroll
  for (int i = 0; i < 4; i++)
#pragma unroll
    for (int j = 0; j < 2; j++) acc[i][j] = (f32x4){0.f, 0.f, 0.f, 0.f};

  const int nt = K >> 5;

#define STAGE16(buf, kt)                                                       \
  do {                                                                         \
    ASYNC16(&Al[buf][(size_t)t * 8], pA0 + (size_t)(kt) * 32);                 \
    ASYNC16(&Al[buf][(size_t)t * 8 + 2048], pA1 + (size_t)(kt) * 32);          \
    ASYNC16(&Bl[buf][(size_t)t * 8], pB + (size_t)(kt) * 32);                  \
  } while (0)

  STAGE16(0, 0);

  const int c = lane >> 4, rl = lane & 15;
  for (int kt = 0; kt < nt; ++kt) {
    asm volatile("s_waitcnt vmcnt(0)" ::: "memory");
    __syncthreads();
    if (kt + 1 < nt) STAGE16((kt + 1) & 1, kt + 1);
    const int buf = kt & 1;
    const _Float16* Ab = &Al[buf][(size_t)(c * 128 + wm * 64 + rl) * 8];
    const _Float16* Bb = &Bl[buf][(size_t)(c * 64 + wn * 32 + rl) * 8];
    half8 af[4], bf[2];
#pragma unroll
    for (int i = 0; i < 4; i++) af[i] = *(const half8*)(Ab + i * 128);
#pragma unroll
    for (int j = 0; j < 2; j++) bf[j] = *(const half8*)(Bb + j * 128);
#pragma unroll
    for (int i = 0; i < 4; i++)
#pragma unroll
      for (int j = 0; j < 2; j++)
        acc[i][j] =
            __builtin_amdgcn_mfma_f32_16x16x32_f16(af[i], bf[j], acc[i][j], 0, 0, 0);
    __syncthreads();
  }

  // epilogue: C/D layout col=lane&15, row=(lane>>4)*4+reg (guide §3, verified)
  const int rb = bm * 128 + wm * 64 + ((lane >> 4) << 2);
  const int cb = bn * 64 + wn * 32 + (lane & 15);
#pragma unroll
  for (int i = 0; i < 4; i++) {
#pragma unroll
    for (int j = 0; j < 2; j++) {
      int col = cb + j * 16;
      if (col >= N) continue;
#pragma unroll
      for (int q = 0; q < 4; q++) {
        int row = rb + i * 16 + q;
        if (row >= M) continue;
        size_t idx = (size_t)row * N + col;
        float v = acc[i][j][q];
        if (mode == MODE_STORE) {
          C[idx] = v;
        } else if (mode == MODE_ADD_BIAS) {
          float bb = bias ? bias[col] : 0.f;
          C[idx] = C[idx] + v + bb;
        } else {  // MODE_SWIGLU16
          float a = aux[idx];
          Ch[idx] = (_Float16)((a / (1.f + expf(-a))) * v);
        }
      }
    }
  }
#undef STAGE16
}

// ---------------------------------------------------------------------------
// fp32 tiled GEMM (kept for small/odd-K GEMMs: embeddings, attn-out, heads)
// ---------------------------------------------------------------------------
__global__ __launch_bounds__(256) void gemm_kernel(
    const float* __restrict__ A, const float* __restrict__ W,
    float* __restrict__ C, const float* __restrict__ bias,
    int M, int N, int K,
    int A_rpb, int A_R, int A_base,
    int C_rpb, int C_R, int C_base,
    int mode) {
  __shared__ __align__(16) float As[16][68];
  __shared__ __align__(16) float Bs[16][68];

  const int t = threadIdx.x;
  const int bm = blockIdx.y, bn = blockIdx.x;
  const int ty = t >> 4, tx = t & 15;
  const int lr = t >> 2;
  const int c0 = (t & 3) * 4;

  const int ma = bm * 64 + lr;
  const bool va = (ma < M);
  int ar = 0;
  if (va) ar = (ma / A_rpb) * A_R + A_base + (ma % A_rpb);
  const float* pA = A + (size_t)ar * K + c0;

  const int nw = bn * 64 + lr;
  const bool vw = (nw < N);
  const float* pW = W + (size_t)nw * K + c0;

  float acc[4][4];
#pragma unroll
  for (int i = 0; i < 4; i++)
#pragma unroll
    for (int j = 0; j < 4; j++) acc[i][j] = 0.f;

  for (int k0 = 0; k0 < K; k0 += 16) {
    __syncthreads();
    float4 avv = va ? *(const float4*)(pA + k0) : make_float4(0.f, 0.f, 0.f, 0.f);
    float4 wvv = vw ? *(const float4*)(pW + k0) : make_float4(0.f, 0.f, 0.f, 0.f);
    As[c0 + 0][lr] = avv.x; As[c0 + 1][lr] = avv.y;
    As[c0 + 2][lr] = avv.z; As[c0 + 3][lr] = avv.w;
    Bs[c0 + 0][lr] = wvv.x; Bs[c0 + 1][lr] = wvv.y;
    Bs[c0 + 2][lr] = wvv.z; Bs[c0 + 3][lr] = wvv.w;
    __syncthreads();
#pragma unroll
    for (int kk = 0; kk < 16; kk++) {
      float4 a = *(const float4*)&As[kk][ty * 4];
      float4 bv = *(const float4*)&Bs[kk][tx * 4];
      float av[4] = {a.x, a.y, a.z, a.w};
      float bb[4] = {bv.x, bv.y, bv.z, bv.w};
#pragma unroll
      for (int i = 0; i < 4; i++)
#pragma unroll
        for (int j = 0; j < 4; j++) acc[i][j] += av[i] * bb[j];
    }
  }

  const int m0 = bm * 64 + ty * 4;
  const int n0 = bn * 64 + tx * 4;
#pragma unroll
  for (int i = 0; i < 4; i++) {
    int m = m0 + i;
    if (m >= M) continue;
    int crow = (m / C_rpb) * C_R + C_base + (m % C_rpb);
    float* cp = C + (size_t)crow * N;
#pragma unroll
    for (int j = 0; j < 4; j++) {
      int n = n0 + j;
      if (n >= N) continue;
      float r = acc[i][j];
      if (mode == MODE_STORE) cp[n] = r;
      else { float bb = bias ? bias[n] : 0.f; cp[n] = cp[n] + r + bb; }
    }
  }
}

// ---------------------------------------------------------------------------
// LayerNorm: one block per row of 512; fp32 math, fp16 output (feeds MFMA)
// ---------------------------------------------------------------------------
__global__ __launch_bounds__(256) void ln_kernel(
    const float* __restrict__ x, const float* __restrict__ g,
    const float* __restrict__ b, _Float16* __restrict__ out) {
  const int row = blockIdx.x;
  const int t = threadIdx.x;
  const float* xr = x + (size_t)row * D_;
  float v0 = xr[t], v1 = xr[t + 256];
  float s = v0 + v1, s2 = v0 * v0 + v1 * v1;
#pragma unroll
  for (int o = 32; o > 0; o >>= 1) {
    s += __shfl_down(s, o);
    s2 += __shfl_down(s2, o);
  }
  __shared__ float w1[4], w2[4], mv[2];
  const int w = t >> 6;
  if ((t & 63) == 0) { w1[w] = s; w2[w] = s2; }
  __syncthreads();
  if (t == 0) {
    float ss = w1[0] + w1[1] + w1[2] + w1[3];
    float ss2 = w2[0] + w2[1] + w2[2] + w2[3];
    float mean = ss * (1.f / D_);
    float var = ss2 * (1.f / D_) - mean * mean;
    mv[0] = mean;
    mv[1] = rsqrtf(var + 1e-5f);
  }
  __syncthreads();
  float mean = mv[0], inv = mv[1];
  _Float16* orow = out + (size_t)row * D_;
  orow[t] = (_Float16)((v0 - mean) * inv * g[t] + b[t]);
  orow[t + 256] = (_Float16)((v1 - mean) * inv * g[t + 256] + b[t + 256]);
}

// ---------------------------------------------------------------------------
// fp32 -> fp16 conversion, 8 elems/thread, grid-stride
// ---------------------------------------------------------------------------
__global__ void tohalf_kernel(const float* __restrict__ src,
                              _Float16* __restrict__ dst, int n8) {
  for (int i = blockIdx.x * blockDim.x + threadIdx.x; i < n8;
       i += gridDim.x * blockDim.x) {
    const float4* s = (const float4*)(src + (size_t)i * 8);
    float4 x = s[0], y = s[1];
    half8 h = {(_Float16)x.x, (_Float16)x.y, (_Float16)x.z, (_Float16)x.w,
               (_Float16)y.x, (_Float16)y.y, (_Float16)y.z, (_Float16)y.w};
    *(half8*)(dst + (size_t)i * 8) = h;
  }
}

// ---------------------------------------------------------------------------
// Concat rots/trans/mask into contiguous (B,R,...) buffers
// ---------------------------------------------------------------------------
__global__ void concat_kernel(
    const float* __restrict__ vh_rots, const float* __restrict__ vh_trans,
    const float* __restrict__ vl_rots, const float* __restrict__ vl_trans,
    const float* __restrict__ ep_rots, const float* __restrict__ ep_trans,
    const int* __restrict__ vh_mask, const int* __restrict__ vl_mask,
    const int* __restrict__ ep_mask,
    float* __restrict__ rots, float* __restrict__ trans, int* __restrict__ mask) {
  int idx = blockIdx.x * blockDim.x + threadIdx.x;
  if (idx >= B_ * R_) return;
  int b = idx / R_, r = idx % R_;
  const float* sr; const float* st; int sm;
  if (r < VH_) {
    sr = vh_rots + (size_t)(b * VH_ + r) * 9;
    st = vh_trans + (size_t)(b * VH_ + r) * 3;
    sm = vh_mask[b * VH_ + r];
  } else if (r < VH_ + VL_) {
    int rr = r - VH_;
    sr = vl_rots + (size_t)(b * VL_ + rr) * 9;
    st = vl_trans + (size_t)(b * VL_ + rr) * 3;
    sm = vl_mask[b * VL_ + rr];
  } else {
    int rr = r - VH_ - VL_;
    sr = ep_rots + (size_t)(b * EP_ + rr) * 9;
    st = ep_trans + (size_t)(b * EP_ + rr) * 3;
    sm = ep_mask[b * EP_ + rr];
  }
#pragma unroll
  for (int k = 0; k < 9; k++) rots[(size_t)idx * 9 + k] = sr[k];
#pragma unroll
  for (int k = 0; k < 3; k++) trans[(size_t)idx * 3 + k] = st[k];
  mask[idx] = sm;
}

// ---------------------------------------------------------------------------
// Build padded mask + zero the j-pad columns of Kt/PKt/Vt (run once per call)
// ---------------------------------------------------------------------------
__global__ void pad_kernel(const int* __restrict__ mask_c, int* __restrict__ maskp,
                           float* __restrict__ Kt, float* __restrict__ PKt,
                           float* __restrict__ Vt) {
  int idx = blockIdx.x * blockDim.x + threadIdx.x;
  if (idx < B_ * RP_) {
    int b = idx >> 9, j = idx & (RP_ - 1);
    maskp[idx] = (j < R_) ? mask_c[b * R_ + j] : 1;
  } else if (idx < B_ * RP_ + 3 * B_ * H_ * 3 * (RP_ - R_)) {
    int p = idx - B_ * RP_;
    int a = p / (B_ * H_ * 3 * (RP_ - R_));
    int q = p % (B_ * H_ * 3 * (RP_ - R_));
    int chan = q / (RP_ - R_), jj = q % (RP_ - R_);
    float* dst = (a == 0) ? Kt : (a == 1) ? PKt : Vt;
    dst[(size_t)chan * RP_ + R_ + jj] = 0.f;
  }
}

// ---------------------------------------------------------------------------
// Positional encoding add for vh (pos=r) and vl (pos=r-VH) rows
// ---------------------------------------------------------------------------
__global__ void pe_kernel(float* __restrict__ emb) {
  int idx = blockIdx.x * blockDim.x + threadIdx.x;
  const int total = B_ * (VH_ + VL_) * D_;
  if (idx >= total) return;
  int d = idx & (D_ - 1);
  int rb = idx >> 9;
  int r = rb % (VH_ + VL_);
  int b = rb / (VH_ + VL_);
  float pos = (r < VH_) ? (float)r : (float)(r - VH_);
  float ang = pos * expf((float)d * (-2.0f / 511.0f) * 6.907755278982137f);
  float enc = (d & 1) ? cosf(ang) : sinf(ang);
  emb[((size_t)b * R_ + r) * D_ + d] += enc;
}

// ---------------------------------------------------------------------------
// Rotate QKV fields; write Q-side row-major, K/V-side transposed [b][h][3][j]
// qkv_raw row layout: [f(5)][h(16)][d(3)]
// ---------------------------------------------------------------------------
__global__ __launch_bounds__(128) void rotate_kernel(
    const float* __restrict__ qkv_raw, const float* __restrict__ rots,
    const float* __restrict__ trans, float* __restrict__ Qrow,
    float* __restrict__ PQrow, float* __restrict__ Kt,
    float* __restrict__ PKt, float* __restrict__ Vt) {
  const int blk = blockIdx.x;
  const int b = blk / R_;
  const int r = blk % R_;
  const int t = threadIdx.x;
  __shared__ float Rm[9], tr[3], raw[240];
  if (t < 9) Rm[t] = rots[(size_t)blk * 9 + t];
  if (t >= 9 && t < 12) tr[t - 9] = trans[(size_t)blk * 3 + (t - 9)];
  for (int i = t; i < 240; i += 128) raw[i] = qkv_raw[(size_t)blk * 240 + i];
  __syncthreads();
  if (t < 80) {
    int f = t / 16, h = t % 16;
    float x = raw[f * 48 + h * 3 + 0];
    float y = raw[f * 48 + h * 3 + 1];
    float z = raw[f * 48 + h * 3 + 2];
    float r0 = Rm[0] * x + Rm[1] * y + Rm[2] * z;
    float r1 = Rm[3] * x + Rm[4] * y + Rm[5] * z;
    float r2 = Rm[6] * x + Rm[7] * y + Rm[8] * z;
    if (f == 2 || f == 3) { r0 += tr[0]; r1 += tr[1]; r2 += tr[2]; }
    if (f == 0 || f == 2) {
      float* dst = (f == 0) ? Qrow : PQrow;
      size_t o = (size_t)blk * 48 + h * 3;
      dst[o] = r0; dst[o + 1] = r1; dst[o + 2] = r2;
    } else {
      float* dst = (f == 1) ? Kt : (f == 3) ? PKt : Vt;
      size_t base = ((size_t)(b * H_ + h) * 3) * RP_ + r;
      dst[base] = r0; dst[base + RP_] = r1; dst[base + 2 * RP_] = r2;
    }
  }
}

// ---------------------------------------------------------------------------
// Attention v2: block per (b, i-pair); 4 waves x 4 heads; wave-shuffle
// softmax; coalesced transposed K/Pk/V reads; inverse-rotate epilogue.
// ---------------------------------------------------------------------------
__global__ __launch_bounds__(256) void attn2_kernel(
    const float* __restrict__ Qrow, const float* __restrict__ PQrow,
    const float* __restrict__ Kt, const float* __restrict__ PKt,
    const float* __restrict__ Vt, const float* __restrict__ rots,
    const int* __restrict__ mask, const int* __restrict__ maskp,
    const float* __restrict__ rs, const float* __restrict__ ds,
    float* __restrict__ o) {
  const int blk = blockIdx.x;
  const int b = blk / (R_ / 2);
  const int ip = blk % (R_ / 2);
  const int i0 = ip * 2;
  const int t = threadIdx.x;
  const int lane = t & 63;
  const int w = t >> 6;

  __shared__ float qs[2][48], ps[2][48], og[2][48];
  __shared__ float crs[16], cds[16];
  __shared__ int mi[2];

  if (t < 96) {
    int io = t / 48, k2 = t % 48;
    int i = i0 + io;
    qs[io][k2] = Qrow[((size_t)(b * R_ + i)) * 48 + k2];
    ps[io][k2] = PQrow[((size_t)(b * R_ + i)) * 48 + k2];
  } else if (t < 112) {
    int h = t - 96;
    const float sc = 0.57735026918962576f;
    crs[h] = log1pf(expf(rs[h])) * sc;
    cds[h] = log1pf(expf(ds[h])) * sc;
  } else if (t < 114) {
    mi[t - 112] = mask[b * R_ + i0 + (t - 112)];
  }
  __syncthreads();

  float mb[8];
#pragma unroll
  for (int jb = 0; jb < 8; jb++) {
    int j = jb * 64 + lane;
    mb[jb] = maskp[b * RP_ + j] ? -1e9f : 0.f;
  }
  const float bi0 = mi[0] ? -1e9f : 0.f;
  const float bi1 = mi[1] ? -1e9f : 0.f;

  for (int hh = 0; hh < 4; hh++) {
    const int h = hh * 4 + w;
    const float sA = crs[h], sD = cds[h];
    const float qx0 = qs[0][h * 3], qy0 = qs[0][h * 3 + 1], qz0 = qs[0][h * 3 + 2];
    const float px0 = ps[0][h * 3], py0 = ps[0][h * 3 + 1], pz0 = ps[0][h * 3 + 2];
    const float qx1 = qs[1][h * 3], qy1 = qs[1][h * 3 + 1], qz1 = qs[1][h * 3 + 2];
    const float px1 = ps[1][h * 3], py1 = ps[1][h * 3 + 1], pz1 = ps[1][h * 3 + 2];
    const float* kb = Kt + ((size_t)(b * H_ + h) * 3) * RP_;
    const float* pb = PKt + ((size_t)(b * H_ + h) * 3) * RP_;
    const float* vb = Vt + ((size_t)(b * H_ + h) * 3) * RP_;

    float l0[8], l1[8];
    float m0 = -3e38f, m1 = -3e38f;
#pragma unroll
    for (int jb = 0; jb < 8; jb++) {
      int j = jb * 64 + lane;
      float kx = kb[j], ky = kb[j + RP_], kz = kb[j + 2 * RP_];
      float pkx = pb[j], pky = pb[j + RP_], pkz = pb[j + 2 * RP_];
      float dx0 = px0 - pkx, dy0 = py0 - pky, dz0 = pz0 - pkz;
      float d0 = sqrtf(dx0 * dx0 + dy0 * dy0 + dz0 * dz0);
      l0[jb] = (qx0 * kx + qy0 * ky + qz0 * kz) * sA - d0 * sD + mb[jb] + bi0;
      m0 = fmaxf(m0, l0[jb]);
      float dx1 = px1 - pkx, dy1 = py1 - pky, dz1 = pz1 - pkz;
      float d1 = sqrtf(dx1 * dx1 + dy1 * dy1 + dz1 * dz1);
      l1[jb] = (qx1 * kx + qy1 * ky + qz1 * kz) * sA - d1 * sD + mb[jb] + bi1;
      m1 = fmaxf(m1, l1[jb]);
    }
#pragma unroll
    for (int s = 1; s < 64; s <<= 1) {
      m0 = fmaxf(m0, __shfl_xor(m0, s));
      m1 = fmaxf(m1, __shfl_xor(m1, s));
    }
    float s0 = 0.f, s1 = 0.f;
    float ox0 = 0.f, oy0 = 0.f, oz0 = 0.f, ox1 = 0.f, oy1 = 0.f, oz1 = 0.f;
#pragma unroll
    for (int jb = 0; jb < 8; jb++) {
      int j = jb * 64 + lane;
      float p0 = expf(l0[jb] - m0);
      float p1 = expf(l1[jb] - m1);
      s0 += p0; s1 += p1;
      float vx = vb[j], vy = vb[j + RP_], vz = vb[j + 2 * RP_];
      ox0 += p0 * vx; oy0 += p0 * vy; oz0 += p0 * vz;
      ox1 += p1 * vx; oy1 += p1 * vy; oz1 += p1 * vz;
    }
#pragma unroll
    for (int s = 1; s < 64; s <<= 1) {
      s0 += __shfl_xor(s0, s); s1 += __shfl_xor(s1, s);
      ox0 += __shfl_xor(ox0, s); oy0 += __shfl_xor(oy0, s); oz0 += __shfl_xor(oz0, s);
      ox1 += __shfl_xor(ox1, s); oy1 += __shfl_xor(oy1, s); oz1 += __shfl_xor(oz1, s);
    }
    if (lane == 0) {
      og[0][h * 3] = ox0 / s0; og[0][h * 3 + 1] = oy0 / s0; og[0][h * 3 + 2] = oz0 / s0;
      og[1][h * 3] = ox1 / s1; og[1][h * 3 + 1] = oy1 / s1; og[1][h * 3 + 2] = oz1 / s1;
    }
  }
  __syncthreads();
  if (t < 96) {
    int io = t / 48, idx = t % 48;
    int h = idx / 3, i3 = idx % 3;
    int i = i0 + io;
    const float* Rm = rots + ((size_t)(b * R_ + i)) * 9;
    float val = Rm[0 + i3] * og[io][h * 3 + 0] +
                Rm[3 + i3] * og[io][h * 3 + 1] +
                Rm[6 + i3] * og[io][h * 3 + 2];
    o[((size_t)(b * R_ + i)) * 48 + idx] = val;
  }
}

// ---------------------------------------------------------------------------
// Output head combine: out = mask ? x : x + t1 * sigmoid(t2 + gate_b)
// ---------------------------------------------------------------------------
__global__ void combine_kernel(
    const float* __restrict__ x, const float* __restrict__ t1,
    const float* __restrict__ t2, const float* __restrict__ gate_b,
    const int* __restrict__ mask, float* __restrict__ out, int total) {
  int idx = blockIdx.x * blockDim.x + threadIdx.x;
  if (idx >= total) return;
  int dm = idx & (DIN_ - 1);
  int row = idx >> 8;
  float xv = x[idx];
  if (mask[row]) {
    out[idx] = xv;
  } else {
    float gate = 1.f / (1.f + expf(-(t2[idx] + gate_b[dm])));
    out[idx] = xv + t1[idx] * gate;
  }
}

// ---------------------------------------------------------------------------
extern "C" void kernel_launch(void* const* d_in, const int* in_sizes, int n_in,
                              void* d_out, int out_size, void* d_ws, size_t ws_size,
                              hipStream_t stream) {
  const float* vh_x = (const float*)d_in[0];
  const float* vl_x = (const float*)d_in[1];
  const float* vh_rots = (const float*)d_in[2];
  const float* vh_trans = (const float*)d_in[3];
  const float* vl_rots = (const float*)d_in[4];
  const float* vl_trans = (const float*)d_in[5];
  const float* ep_feats = (const float*)d_in[6];
  const float* ep_rots = (const float*)d_in[7];
  const float* ep_trans = (const float*)d_in[8];
  const int* vh_mask = (const int*)d_in[9];
  const int* vl_mask = (const int*)d_in[10];
  const int* ep_mask = (const int*)d_in[11];
  const float* vh_emb_w = (const float*)d_in[12];
  const float* vl_emb_w = (const float*)d_in[13];
  const float* tgt_emb_w = (const float*)d_in[14];
  const float* qkv_w = (const float*)d_in[15];
  const float* out_w = (const float*)d_in[16];
  const float* out_b = (const float*)d_in[17];
  const float* ln_g = (const float*)d_in[18];
  const float* ln_b = (const float*)d_in[19];
  const float* r_scale = (const float*)d_in[20];
  const float* d_scale = (const float*)d_in[21];
  const float* ln2_g = (const float*)d_in[22];
  const float* ln2_b = (const float*)d_in[23];
  const float* w12 = (const float*)d_in[24];
  const float* w3 = (const float*)d_in[25];
  const float* out_vh_w = (const float*)d_in[26];
  const float* out_vh_gate_w = (const float*)d_in[27];
  const float* out_vh_gate_b = (const float*)d_in[28];
  const float* out_vl_w = (const float*)d_in[29];
  const float* out_vl_gate_w = (const float*)d_in[30];
  const float* out_vl_gate_b = (const float*)d_in[31];

  const int BR = B_ * R_;  // 2024

  // ---- workspace layout (256B-aligned byte offsets) ----
  uint8_t* P = (uint8_t*)d_ws;
  auto alloc = [&](size_t bytes) {
    uint8_t* p = P;
    P += (bytes + 255) & ~(size_t)255;
    return p;
  };
  float* emb = (float*)alloc((size_t)BR * D_ * 4);
  _Float16* xnh = (_Float16*)alloc((size_t)BR * D_ * 2);
  float* qkvr = (float*)alloc((size_t)BR * 240 * 4);
  float* Qrow = (float*)alloc((size_t)BR * 48 * 4);
  float* PQrow = (float*)alloc((size_t)BR * 48 * 4);
  float* ob = (float*)alloc((size_t)BR * 48 * 4);
  float* Kt = (float*)alloc((size_t)B_ * H_ * 3 * RP_ * 4);
  float* PKt = (float*)alloc((size_t)B_ * H_ * 3 * RP_ * 4);
  float* Vt = (float*)alloc((size_t)B_ * H_ * 3 * RP_ * 4);
  float* gbuf = (float*)alloc((size_t)BR * HID_ * 4);
  _Float16* ghalf = (_Float16*)alloc((size_t)BR * HID_ * 2);
  float* rots_c = (float*)alloc((size_t)BR * 9 * 4);
  float* trans_c = (float*)alloc((size_t)BR * 3 * 4);
  int* mask_c = (int*)alloc((size_t)BR * 4);
  int* maskp = (int*)alloc((size_t)B_ * RP_ * 4);
  float* t1 = (float*)alloc((size_t)B_ * VH_ * DIN_ * 4);
  float* t2 = (float*)alloc((size_t)B_ * VH_ * DIN_ * 4);
  _Float16* qkvh = (_Float16*)alloc((size_t)NL_ * 240 * D_ * 2);
  _Float16* w12h = (_Float16*)alloc((size_t)NL_ * 2 * HID_ * D_ * 2);
  _Float16* w3h = (_Float16*)alloc((size_t)NL_ * D_ * HID_ * 2);

  auto gemm32 = [&](const float* A, const float* W, float* C, const float* bias,
                    int M, int N, int K, int Arpb, int AR, int Abase, int Crpb,
                    int CR, int Cbase, int mode) {
    dim3 g((N + 63) / 64, (M + 63) / 64);
    gemm_kernel<<<g, 256, 0, stream>>>(A, W, C, bias, M, N, K, Arpb, AR, Abase,
                                       Crpb, CR, Cbase, mode);
  };
  auto gemm16 = [&](const _Float16* A, const _Float16* W, float* C,
                    const float* bias, const float* aux, _Float16* Ch, int M,
                    int N, int K, int mode) {
    dim3 g((N + 63) / 64, (M + 127) / 128);
    gemm16_kernel<<<g, 256, 0, stream>>>(A, W, C, bias, aux, Ch, M, N, K, mode);
  };

  // weight conversion to fp16 (every call; graph-safe, deterministic)
  {
    int n8q = NL_ * 240 * D_ / 8;
    int n8a = NL_ * 2 * HID_ * D_ / 8;
    int n8c = NL_ * D_ * HID_ / 8;
    tohalf_kernel<<<dim3(min((n8q + 255) / 256, 2048)), 256, 0, stream>>>(qkv_w, qkvh, n8q);
    tohalf_kernel<<<dim3(min((n8a + 255) / 256, 4096)), 256, 0, stream>>>(w12, w12h, n8a);
    tohalf_kernel<<<dim3(min((n8c + 255) / 256, 4096)), 256, 0, stream>>>(w3, w3h, n8c);
  }

  // concat rots/trans/mask, build padded mask, zero K/V pad columns
  concat_kernel<<<(BR + 255) / 256, 256, 0, stream>>>(
      vh_rots, vh_trans, vl_rots, vl_trans, ep_rots, ep_trans, vh_mask,
      vl_mask, ep_mask, rots_c, trans_c, mask_c);
  {
    int total = B_ * RP_ + 3 * B_ * H_ * 3 * (RP_ - R_);
    pad_kernel<<<(total + 255) / 256, 256, 0, stream>>>(mask_c, maskp, Kt, PKt, Vt);
  }

  // embeddings into emb (row-remapped), fp32
  gemm32(vh_x, vh_emb_w, emb, nullptr, B_ * VH_, D_, DIN_, B_ * VH_, B_ * VH_, 0,
         VH_, R_, 0, MODE_STORE);
  gemm32(vl_x, vl_emb_w, emb, nullptr, B_ * VL_, D_, DIN_, B_ * VL_, B_ * VL_, 0,
         VL_, R_, VH_, MODE_STORE);
  gemm32(ep_feats, tgt_emb_w, emb, nullptr, B_ * EP_, D_, DEP_, B_ * EP_,
         B_ * EP_, 0, EP_, R_, VH_ + VL_, MODE_STORE);
  {
    int total = B_ * (VH_ + VL_) * D_;
    pe_kernel<<<(total + 255) / 256, 256, 0, stream>>>(emb);
  }

  for (int l = 0; l < NL_; l++) {
    const _Float16* qwh = qkvh + (size_t)l * 240 * D_;
    const float* ow = out_w + (size_t)l * D_ * 48;
    const float* obias = out_b + (size_t)l * D_;
    const float* lg = ln_g + (size_t)l * D_;
    const float* lb = ln_b + (size_t)l * D_;
    const float* l2g = ln2_g + (size_t)l * D_;
    const float* l2b = ln2_b + (size_t)l * D_;
    const float* rs = r_scale + (size_t)l * H_;
    const float* dsc = d_scale + (size_t)l * H_;
    const _Float16* w12ah = w12h + (size_t)l * 2 * HID_ * D_;
    const _Float16* w12bh = w12ah + (size_t)HID_ * D_;
    const _Float16* w3lh = w3h + (size_t)l * D_ * HID_;

    // attention
    ln_kernel<<<BR, 256, 0, stream>>>(emb, lg, lb, xnh);
    gemm16(xnh, qwh, qkvr, nullptr, nullptr, nullptr, BR, 240, D_, MODE_STORE);
    rotate_kernel<<<BR, 128, 0, stream>>>(qkvr, rots_c, trans_c, Qrow, PQrow,
                                          Kt, PKt, Vt);
    attn2_kernel<<<B_ * (R_ / 2), 256, 0, stream>>>(Qrow, PQrow, Kt, PKt, Vt,
                                                    rots_c, mask_c, maskp, rs,
                                                    dsc, ob);
    gemm32(ob, ow, emb, obias, BR, D_, 48, BR, BR, 0, BR, BR, 0, MODE_ADD_BIAS);

    // swiglu
    ln_kernel<<<BR, 256, 0, stream>>>(emb, l2g, l2b, xnh);
    gemm16(xnh, w12ah, gbuf, nullptr, nullptr, nullptr, BR, HID_, D_, MODE_STORE);
    gemm16(xnh, w12bh, nullptr, nullptr, gbuf, ghalf, BR, HID_, D_, MODE_SWIGLU16);
    gemm16(ghalf, w3lh, emb, nullptr, nullptr, nullptr, BR, D_, HID_, MODE_ADD_BIAS);
  }

  // output heads (fp32)
  gemm32(emb, out_vh_w, t1, nullptr, B_ * VH_, DIN_, D_, VH_, R_, 0, B_ * VH_,
         B_ * VH_, 0, MODE_STORE);
  gemm32(emb, out_vh_gate_w, t2, nullptr, B_ * VH_, DIN_, D_, VH_, R_, 0,
         B_ * VH_, B_ * VH_, 0, MODE_STORE);
  {
    int total = B_ * VH_ * DIN_;
    combine_kernel<<<(total + 255) / 256, 256, 0, stream>>>(
        vh_x, t1, t2, out_vh_gate_b, vh_mask, (float*)d_out, total);
  }
  gemm32(emb, out_vl_w, t1, nullptr, B_ * VL_, DIN_, D_, VL_, R_, VH_, B_ * VL_,
         B_ * VL_, 0, MODE_STORE);
  gemm32(emb, out_vl_gate_w, t2, nullptr, B_ * VL_, DIN_, D_, VL_, R_, VH_,
         B_ * VL_, B_ * VL_, 0, MODE_STORE);
  {
    int total = B_ * VL_ * DIN_;
    combine_kernel<<<(total + 255) / 256, 256, 0, stream>>>(
        vl_x, t1, t2, out_vl_gate_b, vl_mask,
        (float*)d_out + (size_t)B_ * VH_ * DIN_, total);
  }
}

// Round 5
// 1324.315 us; speedup vs baseline: 3.0439x; 1.3268x over previous
//
#include <hip/hip_runtime.h>
#include <hip/hip_bf16.h>
#include <math.h>
#include <stdint.h>

// Problem constants
#define B_ 4
#define VH_ 130
#define VL_ 120
#define EP_ 256
#define R_ 506           // VH+VL+EP
#define RP_ 512          // padded R for transposed K/V layouts
#define DIN_ 256
#define DEP_ 128
#define D_ 512
#define H_ 16
#define NL_ 8
#define HID_ 2048

#define MODE_STORE 0
#define MODE_ADD_BIAS 1

typedef _Float16 half8 __attribute__((ext_vector_type(8)));
typedef float f32x4 __attribute__((ext_vector_type(4)));

// async global->LDS 16B copy (width literal)
#define ASYNC16(ldsdst, gsrc)                                                  \
  __builtin_amdgcn_global_load_lds(                                            \
      (const __attribute__((address_space(1))) unsigned int*)(gsrc),           \
      (__attribute__((address_space(3))) unsigned int*)(ldsdst), 16, 0, 0)

// ---------------------------------------------------------------------------
// fp16 MFMA GEMM, 4-deep pipelined, counted vmcnt, raw barriers.
// C[m,n] (+)= sum_k A[m,k]*W[n,k].  BM=128 BN=64 BK=32. 256 thr = 4 waves 2x2.
// LDS layout: row-major [row][32 halfs]; read chunk swizzled cp = c^((row>>1)&3)
// staging pre-applies the same involution on the GLOBAL source so each 4-lane
// group covers one row's full 64B segment (coalesced) and reads land right.
// ---------------------------------------------------------------------------
__global__ __launch_bounds__(256) void gemm16_kernel(
    const _Float16* __restrict__ A, const _Float16* __restrict__ W,
    float* __restrict__ C, const float* __restrict__ bias,
    int M, int N, int K, int mode) {
  __shared__ _Float16 Al[4][4096];  // 4 bufs x 128 rows x 32 halfs (32KB)
  __shared__ _Float16 Bl[4][2048];  // 4 bufs x  64 rows x 32 halfs (16KB)

  const int t = threadIdx.x;
  const int nbm = (M + 127) >> 7;
  const int nwg = gridDim.x;
  int bid = blockIdx.x;
  if ((nwg & 7) == 0) {  // bijective XCD swizzle
    int q = nwg >> 3;
    bid = (bid & 7) * q + (bid >> 3);
  }
  const int bm = bid % nbm, bn = bid / nbm;
  const int lane = t & 63;
  const int w = t >> 6;
  const int wm = w >> 1, wn = w & 1;

  // staging: slot s covers (row = s>>2, chunk cp = s&3); source chunk swizzled
  const int r0 = t >> 2;
  const int cp = t & 3;
  const int gc = cp ^ ((r0 >> 1) & 3);
  int gr0 = bm * 128 + r0;       if (gr0 >= M) gr0 = M - 1;
  int gr1 = bm * 128 + 64 + r0;  if (gr1 >= M) gr1 = M - 1;
  int gcol = bn * 64 + r0;       if (gcol >= N) gcol = N - 1;
  const _Float16* pA0 = A + (size_t)gr0 * K + gc * 8;
  const _Float16* pA1 = A + (size_t)gr1 * K + gc * 8;
  const _Float16* pB  = W + (size_t)gcol * K + gc * 8;

#define STAGE(buf, kt)                                                         \
  do {                                                                         \
    ASYNC16(&Al[buf][t * 8], pA0 + (size_t)(kt) * 32);                         \
    ASYNC16(&Al[buf][2048 + t * 8], pA1 + (size_t)(kt) * 32);                  \
    ASYNC16(&Bl[buf][t * 8], pB + (size_t)(kt) * 32);                          \
  } while (0)

  f32x4 acc[4][2];
#pragma unroll
  for (int i = 0; i < 4; i++)
#pragma unroll
    for (int j = 0; j < 2; j++) acc[i][j] = (f32x4){0.f, 0.f, 0.f, 0.f};

  const int nt = K >> 5;  // K-steps (>=8 for all call sites)
  STAGE(0, 0); STAGE(1, 1); STAGE(2, 2);

  const int rl = lane & 15;
  const int ca = (lane >> 4) ^ ((rl >> 1) & 3);  // swizzled chunk for reads
  for (int kt = 0; kt < nt; ++kt) {
    if (kt < nt - 2)       asm volatile("s_waitcnt vmcnt(6)" ::: "memory");
    else if (kt == nt - 2) asm volatile("s_waitcnt vmcnt(3)" ::: "memory");
    else                   asm volatile("s_waitcnt vmcnt(0)" ::: "memory");
    __builtin_amdgcn_s_barrier();
    const int buf = kt & 3;
    const _Float16* Ab = &Al[buf][(wm * 64 + rl) * 32 + ca * 8];
    const _Float16* Bb = &Bl[buf][(wn * 32 + rl) * 32 + ca * 8];
    half8 af[4], bf[2];
#pragma unroll
    for (int i = 0; i < 4; i++) af[i] = *(const half8*)(Ab + i * 512);
#pragma unroll
    for (int j = 0; j < 2; j++) bf[j] = *(const half8*)(Bb + j * 512);
#pragma unroll
    for (int i = 0; i < 4; i++)
#pragma unroll
      for (int j = 0; j < 2; j++)
        acc[i][j] = __builtin_amdgcn_mfma_f32_16x16x32_f16(af[i], bf[j],
                                                           acc[i][j], 0, 0, 0);
    if (kt + 3 < nt) STAGE((kt + 3) & 3, kt + 3);
  }
#undef STAGE

  // epilogue: C/D layout col=lane&15, row=(lane>>4)*4+q
  const int rb = bm * 128 + wm * 64 + ((lane >> 4) << 2);
  const int cb = bn * 64 + wn * 32 + (lane & 15);
#pragma unroll
  for (int i = 0; i < 4; i++) {
#pragma unroll
    for (int j = 0; j < 2; j++) {
      int col = cb + j * 16;
      if (col >= N) continue;
#pragma unroll
      for (int q = 0; q < 4; q++) {
        int row = rb + i * 16 + q;
        if (row >= M) continue;
        size_t idx = (size_t)row * N + col;
        float v = acc[i][j][q];
        if (mode == MODE_STORE) C[idx] = v;
        else {
          float bb = bias ? bias[col] : 0.f;
          C[idx] = C[idx] + v + bb;
        }
      }
    }
  }
}

// ---------------------------------------------------------------------------
// Fused SwiGLU GEMM: ghalf[m,n] = f16( silu(A@Wa^T) * (A@Wv^T) ), N=HID.
// Same pipeline; dual B tiles; eliminates the fp32 gbuf round-trip.
// ---------------------------------------------------------------------------
__global__ __launch_bounds__(256) void gemm16sw_kernel(
    const _Float16* __restrict__ A, const _Float16* __restrict__ Wa,
    const _Float16* __restrict__ Wv, _Float16* __restrict__ Gh,
    int M, int K) {
  __shared__ _Float16 Al[4][4096];
  __shared__ _Float16 Ba[4][2048];
  __shared__ _Float16 Bv[4][2048];

  const int t = threadIdx.x;
  const int nbm = (M + 127) >> 7;
  const int nwg = gridDim.x;
  int bid = blockIdx.x;
  if ((nwg & 7) == 0) {
    int q = nwg >> 3;
    bid = (bid & 7) * q + (bid >> 3);
  }
  const int bm = bid % nbm, bn = bid / nbm;
  const int lane = t & 63;
  const int w = t >> 6;
  const int wm = w >> 1, wn = w & 1;

  const int r0 = t >> 2;
  const int cp = t & 3;
  const int gc = cp ^ ((r0 >> 1) & 3);
  int gr0 = bm * 128 + r0;       if (gr0 >= M) gr0 = M - 1;
  int gr1 = bm * 128 + 64 + r0;  if (gr1 >= M) gr1 = M - 1;
  const int gcol = bn * 64 + r0;  // N=2048 exact, no clamp
  const _Float16* pA0 = A + (size_t)gr0 * K + gc * 8;
  const _Float16* pA1 = A + (size_t)gr1 * K + gc * 8;
  const _Float16* pBa = Wa + (size_t)gcol * K + gc * 8;
  const _Float16* pBv = Wv + (size_t)gcol * K + gc * 8;

#define STAGE(buf, kt)                                                         \
  do {                                                                         \
    ASYNC16(&Al[buf][t * 8], pA0 + (size_t)(kt) * 32);                         \
    ASYNC16(&Al[buf][2048 + t * 8], pA1 + (size_t)(kt) * 32);                  \
    ASYNC16(&Ba[buf][t * 8], pBa + (size_t)(kt) * 32);                         \
    ASYNC16(&Bv[buf][t * 8], pBv + (size_t)(kt) * 32);                         \
  } while (0)

  f32x4 aca[4][2], acv[4][2];
#pragma unroll
  for (int i = 0; i < 4; i++)
#pragma unroll
    for (int j = 0; j < 2; j++) {
      aca[i][j] = (f32x4){0.f, 0.f, 0.f, 0.f};
      acv[i][j] = (f32x4){0.f, 0.f, 0.f, 0.f};
    }

  const int nt = K >> 5;
  STAGE(0, 0); STAGE(1, 1); STAGE(2, 2);

  const int rl = lane & 15;
  const int ca = (lane >> 4) ^ ((rl >> 1) & 3);
  for (int kt = 0; kt < nt; ++kt) {
    if (kt < nt - 2)       asm volatile("s_waitcnt vmcnt(8)" ::: "memory");
    else if (kt == nt - 2) asm volatile("s_waitcnt vmcnt(4)" ::: "memory");
    else                   asm volatile("s_waitcnt vmcnt(0)" ::: "memory");
    __builtin_amdgcn_s_barrier();
    const int buf = kt & 3;
    const _Float16* Ab  = &Al[buf][(wm * 64 + rl) * 32 + ca * 8];
    const _Float16* Bab = &Ba[buf][(wn * 32 + rl) * 32 + ca * 8];
    const _Float16* Bvb = &Bv[buf][(wn * 32 + rl) * 32 + ca * 8];
    half8 af[4], bfa[2], bfv[2];
#pragma unroll
    for (int i = 0; i < 4; i++) af[i] = *(const half8*)(Ab + i * 512);
#pragma unroll
    for (int j = 0; j < 2; j++) {
      bfa[j] = *(const half8*)(Bab + j * 512);
      bfv[j] = *(const half8*)(Bvb + j * 512);
    }
#pragma unroll
    for (int i = 0; i < 4; i++)
#pragma unroll
      for (int j = 0; j < 2; j++) {
        aca[i][j] = __builtin_amdgcn_mfma_f32_16x16x32_f16(af[i], bfa[j],
                                                           aca[i][j], 0, 0, 0);
        acv[i][j] = __builtin_amdgcn_mfma_f32_16x16x32_f16(af[i], bfv[j],
                                                           acv[i][j], 0, 0, 0);
      }
    if (kt + 3 < nt) STAGE((kt + 3) & 3, kt + 3);
  }
#undef STAGE

  const int rb = bm * 128 + wm * 64 + ((lane >> 4) << 2);
  const int cb = bn * 64 + wn * 32 + (lane & 15);
#pragma unroll
  for (int i = 0; i < 4; i++) {
#pragma unroll
    for (int j = 0; j < 2; j++) {
      int col = cb + j * 16;
#pragma unroll
      for (int q = 0; q < 4; q++) {
        int row = rb + i * 16 + q;
        if (row >= M) continue;
        float a = aca[i][j][q];
        float v = acv[i][j][q];
        Gh[(size_t)row * HID_ + col] = (_Float16)((a / (1.f + expf(-a))) * v);
      }
    }
  }
}

// ---------------------------------------------------------------------------
// fp32 tiled GEMM (embeddings, attn-out K=48, output heads)
// ---------------------------------------------------------------------------
__global__ __launch_bounds__(256) void gemm_kernel(
    const float* __restrict__ A, const float* __restrict__ W,
    float* __restrict__ C, const float* __restrict__ bias,
    int M, int N, int K,
    int A_rpb, int A_R, int A_base,
    int C_rpb, int C_R, int C_base,
    int mode) {
  __shared__ __align__(16) float As[16][68];
  __shared__ __align__(16) float Bs[16][68];

  const int t = threadIdx.x;
  const int bm = blockIdx.y, bn = blockIdx.x;
  const int ty = t >> 4, tx = t & 15;
  const int lr = t >> 2;
  const int c0 = (t & 3) * 4;

  const int ma = bm * 64 + lr;
  const bool va = (ma < M);
  int ar = 0;
  if (va) ar = (ma / A_rpb) * A_R + A_base + (ma % A_rpb);
  const float* pA = A + (size_t)ar * K + c0;

  const int nw = bn * 64 + lr;
  const bool vw = (nw < N);
  const float* pW = W + (size_t)nw * K + c0;

  float acc[4][4];
#pragma unroll
  for (int i = 0; i < 4; i++)
#pragma unroll
    for (int j = 0; j < 4; j++) acc[i][j] = 0.f;

  for (int k0 = 0; k0 < K; k0 += 16) {
    __syncthreads();
    float4 avv = va ? *(const float4*)(pA + k0) : make_float4(0.f, 0.f, 0.f, 0.f);
    float4 wvv = vw ? *(const float4*)(pW + k0) : make_float4(0.f, 0.f, 0.f, 0.f);
    As[c0 + 0][lr] = avv.x; As[c0 + 1][lr] = avv.y;
    As[c0 + 2][lr] = avv.z; As[c0 + 3][lr] = avv.w;
    Bs[c0 + 0][lr] = wvv.x; Bs[c0 + 1][lr] = wvv.y;
    Bs[c0 + 2][lr] = wvv.z; Bs[c0 + 3][lr] = wvv.w;
    __syncthreads();
#pragma unroll
    for (int kk = 0; kk < 16; kk++) {
      float4 a = *(const float4*)&As[kk][ty * 4];
      float4 bv = *(const float4*)&Bs[kk][tx * 4];
      float av[4] = {a.x, a.y, a.z, a.w};
      float bb[4] = {bv.x, bv.y, bv.z, bv.w};
#pragma unroll
      for (int i = 0; i < 4; i++)
#pragma unroll
        for (int j = 0; j < 4; j++) acc[i][j] += av[i] * bb[j];
    }
  }

  const int m0 = bm * 64 + ty * 4;
  const int n0 = bn * 64 + tx * 4;
#pragma unroll
  for (int i = 0; i < 4; i++) {
    int m = m0 + i;
    if (m >= M) continue;
    int crow = (m / C_rpb) * C_R + C_base + (m % C_rpb);
    float* cp = C + (size_t)crow * N;
#pragma unroll
    for (int j = 0; j < 4; j++) {
      int n = n0 + j;
      if (n >= N) continue;
      float r = acc[i][j];
      if (mode == MODE_STORE) cp[n] = r;
      else { float bb = bias ? bias[n] : 0.f; cp[n] = cp[n] + r + bb; }
    }
  }
}

// ---------------------------------------------------------------------------
// LayerNorm: one block per row of 512; fp32 math, fp16 output
// ---------------------------------------------------------------------------
__global__ __launch_bounds__(256) void ln_kernel(
    const float* __restrict__ x, const float* __restrict__ g,
    const float* __restrict__ b, _Float16* __restrict__ out) {
  const int row = blockIdx.x;
  const int t = threadIdx.x;
  const float* xr = x + (size_t)row * D_;
  float v0 = xr[t], v1 = xr[t + 256];
  float s = v0 + v1, s2 = v0 * v0 + v1 * v1;
#pragma unroll
  for (int o = 32; o > 0; o >>= 1) {
    s += __shfl_down(s, o);
    s2 += __shfl_down(s2, o);
  }
  __shared__ float w1[4], w2[4], mv[2];
  const int w = t >> 6;
  if ((t & 63) == 0) { w1[w] = s; w2[w] = s2; }
  __syncthreads();
  if (t == 0) {
    float ss = w1[0] + w1[1] + w1[2] + w1[3];
    float ss2 = w2[0] + w2[1] + w2[2] + w2[3];
    float mean = ss * (1.f / D_);
    float var = ss2 * (1.f / D_) - mean * mean;
    mv[0] = mean;
    mv[1] = rsqrtf(var + 1e-5f);
  }
  __syncthreads();
  float mean = mv[0], inv = mv[1];
  _Float16* orow = out + (size_t)row * D_;
  orow[t] = (_Float16)((v0 - mean) * inv * g[t] + b[t]);
  orow[t + 256] = (_Float16)((v1 - mean) * inv * g[t + 256] + b[t + 256]);
}

// ---------------------------------------------------------------------------
__global__ void tohalf_kernel(const float* __restrict__ src,
                              _Float16* __restrict__ dst, int n8) {
  for (int i = blockIdx.x * blockDim.x + threadIdx.x; i < n8;
       i += gridDim.x * blockDim.x) {
    const float4* s = (const float4*)(src + (size_t)i * 8);
    float4 x = s[0], y = s[1];
    half8 h = {(_Float16)x.x, (_Float16)x.y, (_Float16)x.z, (_Float16)x.w,
               (_Float16)y.x, (_Float16)y.y, (_Float16)y.z, (_Float16)y.w};
    *(half8*)(dst + (size_t)i * 8) = h;
  }
}

// ---------------------------------------------------------------------------
__global__ void concat_kernel(
    const float* __restrict__ vh_rots, const float* __restrict__ vh_trans,
    const float* __restrict__ vl_rots, const float* __restrict__ vl_trans,
    const float* __restrict__ ep_rots, const float* __restrict__ ep_trans,
    const int* __restrict__ vh_mask, const int* __restrict__ vl_mask,
    const int* __restrict__ ep_mask,
    float* __restrict__ rots, float* __restrict__ trans, int* __restrict__ mask) {
  int idx = blockIdx.x * blockDim.x + threadIdx.x;
  if (idx >= B_ * R_) return;
  int b = idx / R_, r = idx % R_;
  const float* sr; const float* st; int sm;
  if (r < VH_) {
    sr = vh_rots + (size_t)(b * VH_ + r) * 9;
    st = vh_trans + (size_t)(b * VH_ + r) * 3;
    sm = vh_mask[b * VH_ + r];
  } else if (r < VH_ + VL_) {
    int rr = r - VH_;
    sr = vl_rots + (size_t)(b * VL_ + rr) * 9;
    st = vl_trans + (size_t)(b * VL_ + rr) * 3;
    sm = vl_mask[b * VL_ + rr];
  } else {
    int rr = r - VH_ - VL_;
    sr = ep_rots + (size_t)(b * EP_ + rr) * 9;
    st = ep_trans + (size_t)(b * EP_ + rr) * 3;
    sm = ep_mask[b * EP_ + rr];
  }
#pragma unroll
  for (int k = 0; k < 9; k++) rots[(size_t)idx * 9 + k] = sr[k];
#pragma unroll
  for (int k = 0; k < 3; k++) trans[(size_t)idx * 3 + k] = st[k];
  mask[idx] = sm;
}

// ---------------------------------------------------------------------------
__global__ void pad_kernel(const int* __restrict__ mask_c, int* __restrict__ maskp,
                           float* __restrict__ Kt, float* __restrict__ PKt,
                           float* __restrict__ Vt) {
  int idx = blockIdx.x * blockDim.x + threadIdx.x;
  if (idx < B_ * RP_) {
    int b = idx >> 9, j = idx & (RP_ - 1);
    maskp[idx] = (j < R_) ? mask_c[b * R_ + j] : 1;
  } else if (idx < B_ * RP_ + 3 * B_ * H_ * 3 * (RP_ - R_)) {
    int p = idx - B_ * RP_;
    int a = p / (B_ * H_ * 3 * (RP_ - R_));
    int q = p % (B_ * H_ * 3 * (RP_ - R_));
    int chan = q / (RP_ - R_), jj = q % (RP_ - R_);
    float* dst = (a == 0) ? Kt : (a == 1) ? PKt : Vt;
    dst[(size_t)chan * RP_ + R_ + jj] = 0.f;
  }
}

// ---------------------------------------------------------------------------
__global__ void pe_kernel(float* __restrict__ emb) {
  int idx = blockIdx.x * blockDim.x + threadIdx.x;
  const int total = B_ * (VH_ + VL_) * D_;
  if (idx >= total) return;
  int d = idx & (D_ - 1);
  int rb = idx >> 9;
  int r = rb % (VH_ + VL_);
  int b = rb / (VH_ + VL_);
  float pos = (r < VH_) ? (float)r : (float)(r - VH_);
  float ang = pos * expf((float)d * (-2.0f / 511.0f) * 6.907755278982137f);
  float enc = (d & 1) ? cosf(ang) : sinf(ang);
  emb[((size_t)b * R_ + r) * D_ + d] += enc;
}

// ---------------------------------------------------------------------------
__global__ __launch_bounds__(128) void rotate_kernel(
    const float* __restrict__ qkv_raw, const float* __restrict__ rots,
    const float* __restrict__ trans, float* __restrict__ Qrow,
    float* __restrict__ PQrow, float* __restrict__ Kt,
    float* __restrict__ PKt, float* __restrict__ Vt) {
  const int blk = blockIdx.x;
  const int b = blk / R_;
  const int r = blk % R_;
  const int t = threadIdx.x;
  __shared__ float Rm[9], tr[3], raw[240];
  if (t < 9) Rm[t] = rots[(size_t)blk * 9 + t];
  if (t >= 9 && t < 12) tr[t - 9] = trans[(size_t)blk * 3 + (t - 9)];
  for (int i = t; i < 240; i += 128) raw[i] = qkv_raw[(size_t)blk * 240 + i];
  __syncthreads();
  if (t < 80) {
    int f = t / 16, h = t % 16;
    float x = raw[f * 48 + h * 3 + 0];
    float y = raw[f * 48 + h * 3 + 1];
    float z = raw[f * 48 + h * 3 + 2];
    float r0 = Rm[0] * x + Rm[1] * y + Rm[2] * z;
    float r1 = Rm[3] * x + Rm[4] * y + Rm[5] * z;
    float r2 = Rm[6] * x + Rm[7] * y + Rm[8] * z;
    if (f == 2 || f == 3) { r0 += tr[0]; r1 += tr[1]; r2 += tr[2]; }
    if (f == 0 || f == 2) {
      float* dst = (f == 0) ? Qrow : PQrow;
      size_t o = (size_t)blk * 48 + h * 3;
      dst[o] = r0; dst[o + 1] = r1; dst[o + 2] = r2;
    } else {
      float* dst = (f == 1) ? Kt : (f == 3) ? PKt : Vt;
      size_t base = ((size_t)(b * H_ + h) * 3) * RP_ + r;
      dst[base] = r0; dst[base + RP_] = r1; dst[base + 2 * RP_] = r2;
    }
  }
}

// ---------------------------------------------------------------------------
__global__ __launch_bounds__(256) void attn2_kernel(
    const float* __restrict__ Qrow, const float* __restrict__ PQrow,
    const float* __restrict__ Kt, const float* __restrict__ PKt,
    const float* __restrict__ Vt, const float* __restrict__ rots,
    const int* __restrict__ mask, const int* __restrict__ maskp,
    const float* __restrict__ rs, const float* __restrict__ ds,
    float* __restrict__ o) {
  const int blk = blockIdx.x;
  const int b = blk / (R_ / 2);
  const int ip = blk % (R_ / 2);
  const int i0 = ip * 2;
  const int t = threadIdx.x;
  const int lane = t & 63;
  const int w = t >> 6;

  __shared__ float qs[2][48], ps[2][48], og[2][48];
  __shared__ float crs[16], cds[16];
  __shared__ int mi[2];

  if (t < 96) {
    int io = t / 48, k2 = t % 48;
    int i = i0 + io;
    qs[io][k2] = Qrow[((size_t)(b * R_ + i)) * 48 + k2];
    ps[io][k2] = PQrow[((size_t)(b * R_ + i)) * 48 + k2];
  } else if (t < 112) {
    int h = t - 96;
    const float sc = 0.57735026918962576f;
    crs[h] = log1pf(expf(rs[h])) * sc;
    cds[h] = log1pf(expf(ds[h])) * sc;
  } else if (t < 114) {
    mi[t - 112] = mask[b * R_ + i0 + (t - 112)];
  }
  __syncthreads();

  float mb[8];
#pragma unroll
  for (int jb = 0; jb < 8; jb++) {
    int j = jb * 64 + lane;
    mb[jb] = maskp[b * RP_ + j] ? -1e9f : 0.f;
  }
  const float bi0 = mi[0] ? -1e9f : 0.f;
  const float bi1 = mi[1] ? -1e9f : 0.f;

  for (int hh = 0; hh < 4; hh++) {
    const int h = hh * 4 + w;
    const float sA = crs[h], sD = cds[h];
    const float qx0 = qs[0][h * 3], qy0 = qs[0][h * 3 + 1], qz0 = qs[0][h * 3 + 2];
    const float px0 = ps[0][h * 3], py0 = ps[0][h * 3 + 1], pz0 = ps[0][h * 3 + 2];
    const float qx1 = qs[1][h * 3], qy1 = qs[1][h * 3 + 1], qz1 = qs[1][h * 3 + 2];
    const float px1 = ps[1][h * 3], py1 = ps[1][h * 3 + 1], pz1 = ps[1][h * 3 + 2];
    const float* kb = Kt + ((size_t)(b * H_ + h) * 3) * RP_;
    const float* pb = PKt + ((size_t)(b * H_ + h) * 3) * RP_;
    const float* vb = Vt + ((size_t)(b * H_ + h) * 3) * RP_;

    float l0[8], l1[8];
    float m0 = -3e38f, m1 = -3e38f;
#pragma unroll
    for (int jb = 0; jb < 8; jb++) {
      int j = jb * 64 + lane;
      float kx = kb[j], ky = kb[j + RP_], kz = kb[j + 2 * RP_];
      float pkx = pb[j], pky = pb[j + RP_], pkz = pb[j + 2 * RP_];
      float dx0 = px0 - pkx, dy0 = py0 - pky, dz0 = pz0 - pkz;
      float d0 = sqrtf(dx0 * dx0 + dy0 * dy0 + dz0 * dz0);
      l0[jb] = (qx0 * kx + qy0 * ky + qz0 * kz) * sA - d0 * sD + mb[jb] + bi0;
      m0 = fmaxf(m0, l0[jb]);
      float dx1 = px1 - pkx, dy1 = py1 - pky, dz1 = pz1 - pkz;
      float d1 = sqrtf(dx1 * dx1 + dy1 * dy1 + dz1 * dz1);
      l1[jb] = (qx1 * kx + qy1 * ky + qz1 * kz) * sA - d1 * sD + mb[jb] + bi1;
      m1 = fmaxf(m1, l1[jb]);
    }
#pragma unroll
    for (int s = 1; s < 64; s <<= 1) {
      m0 = fmaxf(m0, __shfl_xor(m0, s));
      m1 = fmaxf(m1, __shfl_xor(m1, s));
    }
    float s0 = 0.f, s1 = 0.f;
    float ox0 = 0.f, oy0 = 0.f, oz0 = 0.f, ox1 = 0.f, oy1 = 0.f, oz1 = 0.f;
#pragma unroll
    for (int jb = 0; jb < 8; jb++) {
      int j = jb * 64 + lane;
      float p0 = expf(l0[jb] - m0);
      float p1 = expf(l1[jb] - m1);
      s0 += p0; s1 += p1;
      float vx = vb[j], vy = vb[j + RP_], vz = vb[j + 2 * RP_];
      ox0 += p0 * vx; oy0 += p0 * vy; oz0 += p0 * vz;
      ox1 += p1 * vx; oy1 += p1 * vy; oz1 += p1 * vz;
    }
#pragma unroll
    for (int s = 1; s < 64; s <<= 1) {
      s0 += __shfl_xor(s0, s); s1 += __shfl_xor(s1, s);
      ox0 += __shfl_xor(ox0, s); oy0 += __shfl_xor(oy0, s); oz0 += __shfl_xor(oz0, s);
      ox1 += __shfl_xor(ox1, s); oy1 += __shfl_xor(oy1, s); oz1 += __shfl_xor(oz1, s);
    }
    if (lane == 0) {
      og[0][h * 3] = ox0 / s0; og[0][h * 3 + 1] = oy0 / s0; og[0][h * 3 + 2] = oz0 / s0;
      og[1][h * 3] = ox1 / s1; og[1][h * 3 + 1] = oy1 / s1; og[1][h * 3 + 2] = oz1 / s1;
    }
  }
  __syncthreads();
  if (t < 96) {
    int io = t / 48, idx = t % 48;
    int h = idx / 3, i3 = idx % 3;
    int i = i0 + io;
    const float* Rm = rots + ((size_t)(b * R_ + i)) * 9;
    float val = Rm[0 + i3] * og[io][h * 3 + 0] +
                Rm[3 + i3] * og[io][h * 3 + 1] +
                Rm[6 + i3] * og[io][h * 3 + 2];
    o[((size_t)(b * R_ + i)) * 48 + idx] = val;
  }
}

// ---------------------------------------------------------------------------
__global__ void combine_kernel(
    const float* __restrict__ x, const float* __restrict__ t1,
    const float* __restrict__ t2, const float* __restrict__ gate_b,
    const int* __restrict__ mask, float* __restrict__ out, int total) {
  int idx = blockIdx.x * blockDim.x + threadIdx.x;
  if (idx >= total) return;
  int dm = idx & (DIN_ - 1);
  int row = idx >> 8;
  float xv = x[idx];
  if (mask[row]) {
    out[idx] = xv;
  } else {
    float gate = 1.f / (1.f + expf(-(t2[idx] + gate_b[dm])));
    out[idx] = xv + t1[idx] * gate;
  }
}

// ---------------------------------------------------------------------------
extern "C" void kernel_launch(void* const* d_in, const int* in_sizes, int n_in,
                              void* d_out, int out_size, void* d_ws, size_t ws_size,
                              hipStream_t stream) {
  const float* vh_x = (const float*)d_in[0];
  const float* vl_x = (const float*)d_in[1];
  const float* vh_rots = (const float*)d_in[2];
  const float* vh_trans = (const float*)d_in[3];
  const float* vl_rots = (const float*)d_in[4];
  const float* vl_trans = (const float*)d_in[5];
  const float* ep_feats = (const float*)d_in[6];
  const float* ep_rots = (const float*)d_in[7];
  const float* ep_trans = (const float*)d_in[8];
  const int* vh_mask = (const int*)d_in[9];
  const int* vl_mask = (const int*)d_in[10];
  const int* ep_mask = (const int*)d_in[11];
  const float* vh_emb_w = (const float*)d_in[12];
  const float* vl_emb_w = (const float*)d_in[13];
  const float* tgt_emb_w = (const float*)d_in[14];
  const float* qkv_w = (const float*)d_in[15];
  const float* out_w = (const float*)d_in[16];
  const float* out_b = (const float*)d_in[17];
  const float* ln_g = (const float*)d_in[18];
  const float* ln_b = (const float*)d_in[19];
  const float* r_scale = (const float*)d_in[20];
  const float* d_scale = (const float*)d_in[21];
  const float* ln2_g = (const float*)d_in[22];
  const float* ln2_b = (const float*)d_in[23];
  const float* w12 = (const float*)d_in[24];
  const float* w3 = (const float*)d_in[25];
  const float* out_vh_w = (const float*)d_in[26];
  const float* out_vh_gate_w = (const float*)d_in[27];
  const float* out_vh_gate_b = (const float*)d_in[28];
  const float* out_vl_w = (const float*)d_in[29];
  const float* out_vl_gate_w = (const float*)d_in[30];
  const float* out_vl_gate_b = (const float*)d_in[31];

  const int BR = B_ * R_;  // 2024

  // ---- workspace layout (256B-aligned) ----
  uint8_t* P = (uint8_t*)d_ws;
  auto alloc = [&](size_t bytes) {
    uint8_t* p = P;
    P += (bytes + 255) & ~(size_t)255;
    return p;
  };
  float* emb = (float*)alloc((size_t)BR * D_ * 4);
  _Float16* xnh = (_Float16*)alloc((size_t)BR * D_ * 2);
  float* qkvr = (float*)alloc((size_t)BR * 240 * 4);
  float* Qrow = (float*)alloc((size_t)BR * 48 * 4);
  float* PQrow = (float*)alloc((size_t)BR * 48 * 4);
  float* ob = (float*)alloc((size_t)BR * 48 * 4);
  float* Kt = (float*)alloc((size_t)B_ * H_ * 3 * RP_ * 4);
  float* PKt = (float*)alloc((size_t)B_ * H_ * 3 * RP_ * 4);
  float* Vt = (float*)alloc((size_t)B_ * H_ * 3 * RP_ * 4);
  _Float16* ghalf = (_Float16*)alloc((size_t)BR * HID_ * 2);
  float* rots_c = (float*)alloc((size_t)BR * 9 * 4);
  float* trans_c = (float*)alloc((size_t)BR * 3 * 4);
  int* mask_c = (int*)alloc((size_t)BR * 4);
  int* maskp = (int*)alloc((size_t)B_ * RP_ * 4);
  float* t1 = (float*)alloc((size_t)B_ * VH_ * DIN_ * 4);
  float* t2 = (float*)alloc((size_t)B_ * VH_ * DIN_ * 4);
  _Float16* qkvh = (_Float16*)alloc((size_t)NL_ * 240 * D_ * 2);
  _Float16* w12h = (_Float16*)alloc((size_t)NL_ * 2 * HID_ * D_ * 2);
  _Float16* w3h = (_Float16*)alloc((size_t)NL_ * D_ * HID_ * 2);

  auto gemm32 = [&](const float* A, const float* W, float* C, const float* bias,
                    int M, int N, int K, int Arpb, int AR, int Abase, int Crpb,
                    int CR, int Cbase, int mode) {
    dim3 g((N + 63) / 64, (M + 63) / 64);
    gemm_kernel<<<g, 256, 0, stream>>>(A, W, C, bias, M, N, K, Arpb, AR, Abase,
                                       Crpb, CR, Cbase, mode);
  };
  auto gemm16 = [&](const _Float16* A, const _Float16* W, float* C,
                    const float* bias, int M, int N, int K, int mode) {
    int nbm = (M + 127) / 128, nbn = (N + 63) / 64;
    gemm16_kernel<<<nbm * nbn, 256, 0, stream>>>(A, W, C, bias, M, N, K, mode);
  };

  // weight conversion to fp16
  {
    int n8q = NL_ * 240 * D_ / 8;
    int n8a = NL_ * 2 * HID_ * D_ / 8;
    int n8c = NL_ * D_ * HID_ / 8;
    tohalf_kernel<<<dim3(min((n8q + 255) / 256, 2048)), 256, 0, stream>>>(qkv_w, qkvh, n8q);
    tohalf_kernel<<<dim3(min((n8a + 255) / 256, 4096)), 256, 0, stream>>>(w12, w12h, n8a);
    tohalf_kernel<<<dim3(min((n8c + 255) / 256, 4096)), 256, 0, stream>>>(w3, w3h, n8c);
  }

  concat_kernel<<<(BR + 255) / 256, 256, 0, stream>>>(
      vh_rots, vh_trans, vl_rots, vl_trans, ep_rots, ep_trans, vh_mask,
      vl_mask, ep_mask, rots_c, trans_c, mask_c);
  {
    int total = B_ * RP_ + 3 * B_ * H_ * 3 * (RP_ - R_);
    pad_kernel<<<(total + 255) / 256, 256, 0, stream>>>(mask_c, maskp, Kt, PKt, Vt);
  }

  // embeddings (fp32)
  gemm32(vh_x, vh_emb_w, emb, nullptr, B_ * VH_, D_, DIN_, B_ * VH_, B_ * VH_, 0,
         VH_, R_, 0, MODE_STORE);
  gemm32(vl_x, vl_emb_w, emb, nullptr, B_ * VL_, D_, DIN_, B_ * VL_, B_ * VL_, 0,
         VL_, R_, VH_, MODE_STORE);
  gemm32(ep_feats, tgt_emb_w, emb, nullptr, B_ * EP_, D_, DEP_, B_ * EP_,
         B_ * EP_, 0, EP_, R_, VH_ + VL_, MODE_STORE);
  {
    int total = B_ * (VH_ + VL_) * D_;
    pe_kernel<<<(total + 255) / 256, 256, 0, stream>>>(emb);
  }

  for (int l = 0; l < NL_; l++) {
    const _Float16* qwh = qkvh + (size_t)l * 240 * D_;
    const float* ow = out_w + (size_t)l * D_ * 48;
    const float* obias = out_b + (size_t)l * D_;
    const float* lg = ln_g + (size_t)l * D_;
    const float* lb = ln_b + (size_t)l * D_;
    const float* l2g = ln2_g + (size_t)l * D_;
    const float* l2b = ln2_b + (size_t)l * D_;
    const float* rs = r_scale + (size_t)l * H_;
    const float* dsc = d_scale + (size_t)l * H_;
    const _Float16* w12ah = w12h + (size_t)l * 2 * HID_ * D_;
    const _Float16* w12bh = w12ah + (size_t)HID_ * D_;
    const _Float16* w3lh = w3h + (size_t)l * D_ * HID_;

    // attention
    ln_kernel<<<BR, 256, 0, stream>>>(emb, lg, lb, xnh);
    gemm16(xnh, qwh, qkvr, nullptr, BR, 240, D_, MODE_STORE);
    rotate_kernel<<<BR, 128, 0, stream>>>(qkvr, rots_c, trans_c, Qrow, PQrow,
                                          Kt, PKt, Vt);
    attn2_kernel<<<B_ * (R_ / 2), 256, 0, stream>>>(Qrow, PQrow, Kt, PKt, Vt,
                                                    rots_c, mask_c, maskp, rs,
                                                    dsc, ob);
    gemm32(ob, ow, emb, obias, BR, D_, 48, BR, BR, 0, BR, BR, 0, MODE_ADD_BIAS);

    // swiglu (fused a/v GEMM -> ghalf, then w3)
    ln_kernel<<<BR, 256, 0, stream>>>(emb, l2g, l2b, xnh);
    {
      int nbm = (BR + 127) / 128, nbn = HID_ / 64;
      gemm16sw_kernel<<<nbm * nbn, 256, 0, stream>>>(xnh, w12ah, w12bh, ghalf,
                                                     BR, D_);
    }
    gemm16(ghalf, w3lh, emb, nullptr, BR, D_, HID_, MODE_ADD_BIAS);
  }

  // output heads (fp32)
  gemm32(emb, out_vh_w, t1, nullptr, B_ * VH_, DIN_, D_, VH_, R_, 0, B_ * VH_,
         B_ * VH_, 0, MODE_STORE);
  gemm32(emb, out_vh_gate_w, t2, nullptr, B_ * VH_, DIN_, D_, VH_, R_, 0,
         B_ * VH_, B_ * VH_, 0, MODE_STORE);
  {
    int total = B_ * VH_ * DIN_;
    combine_kernel<<<(total + 255) / 256, 256, 0, stream>>>(
        vh_x, t1, t2, out_vh_gate_b, vh_mask, (float*)d_out, total);
  }
  gemm32(emb, out_vl_w, t1, nullptr, B_ * VL_, DIN_, D_, VL_, R_, VH_, B_ * VL_,
         B_ * VL_, 0, MODE_STORE);
  gemm32(emb, out_vl_gate_w, t2, nullptr, B_ * VL_, DIN_, D_, VL_, R_, VH_,
         B_ * VL_, B_ * VL_, 0, MODE_STORE);
  {
    int total = B_ * VL_ * DIN_;
    combine_kernel<<<(total + 255) / 256, 256, 0, stream>>>(
        vl_x, t1, t2, out_vl_gate_b, vl_mask,
        (float*)d_out + (size_t)B_ * VH_ * DIN_, total);
  }
}

// Round 7
// 1312.128 us; speedup vs baseline: 3.0722x; 1.0093x over previous
//
#include <hip/hip_runtime.h>
#include <hip/hip_bf16.h>
#include <math.h>
#include <stdint.h>

// Problem constants
#define B_ 4
#define VH_ 130
#define VL_ 120
#define EP_ 256
#define R_ 506           // VH+VL+EP
#define RP_ 512          // padded R for transposed K/V layouts
#define DIN_ 256
#define DEP_ 128
#define D_ 512
#define H_ 16
#define NL_ 8
#define HID_ 2048

#define MODE_STORE 0
#define MODE_ADD_BIAS 1

typedef _Float16 half8 __attribute__((ext_vector_type(8)));
typedef float f32x4 __attribute__((ext_vector_type(4)));

// async global->LDS 16B copy (width literal)
#define ASYNC16(ldsdst, gsrc)                                                  \
  __builtin_amdgcn_global_load_lds(                                            \
      (const __attribute__((address_space(1))) unsigned int*)(gsrc),           \
      (__attribute__((address_space(3))) unsigned int*)(ldsdst), 16, 0, 0)

// ---------------------------------------------------------------------------
// fp16 MFMA GEMM, BM=128 BN=64, 4-deep pipeline, fused SwiGLU (dual-B).
// ghalf[m,n] = f16( silu(A@Wa^T) * (A@Wv^T) ), N=HID. (validated round 5)
// ---------------------------------------------------------------------------
__global__ __launch_bounds__(256) void gemm16sw_kernel(
    const _Float16* __restrict__ A, const _Float16* __restrict__ Wa,
    const _Float16* __restrict__ Wv, _Float16* __restrict__ Gh,
    int M, int K) {
  __shared__ _Float16 Al[4][4096];
  __shared__ _Float16 Ba[4][2048];
  __shared__ _Float16 Bv[4][2048];

  const int t = threadIdx.x;
  const int nbm = (M + 127) >> 7;
  const int nwg = gridDim.x;
  int bid = blockIdx.x;
  if ((nwg & 7) == 0) {
    int q = nwg >> 3;
    bid = (bid & 7) * q + (bid >> 3);
  }
  const int bm = bid % nbm, bn = bid / nbm;
  const int lane = t & 63;
  const int w = t >> 6;
  const int wm = w >> 1, wn = w & 1;

  const int r0 = t >> 2;
  const int cp = t & 3;
  const int gc = cp ^ ((r0 >> 1) & 3);
  int gr0 = bm * 128 + r0;       if (gr0 >= M) gr0 = M - 1;
  int gr1 = bm * 128 + 64 + r0;  if (gr1 >= M) gr1 = M - 1;
  const int gcol = bn * 64 + r0;  // N=2048 exact
  const _Float16* pA0 = A + (size_t)gr0 * K + gc * 8;
  const _Float16* pA1 = A + (size_t)gr1 * K + gc * 8;
  const _Float16* pBa = Wa + (size_t)gcol * K + gc * 8;
  const _Float16* pBv = Wv + (size_t)gcol * K + gc * 8;

#define STAGE(buf, kt)                                                         \
  do {                                                                         \
    ASYNC16(&Al[buf][t * 8], pA0 + (size_t)(kt) * 32);                         \
    ASYNC16(&Al[buf][2048 + t * 8], pA1 + (size_t)(kt) * 32);                  \
    ASYNC16(&Ba[buf][t * 8], pBa + (size_t)(kt) * 32);                         \
    ASYNC16(&Bv[buf][t * 8], pBv + (size_t)(kt) * 32);                         \
  } while (0)

  f32x4 aca[4][2], acv[4][2];
#pragma unroll
  for (int i = 0; i < 4; i++)
#pragma unroll
    for (int j = 0; j < 2; j++) {
      aca[i][j] = (f32x4){0.f, 0.f, 0.f, 0.f};
      acv[i][j] = (f32x4){0.f, 0.f, 0.f, 0.f};
    }

  const int nt = K >> 5;
  STAGE(0, 0); STAGE(1, 1); STAGE(2, 2);

  const int rl = lane & 15;
  const int ca = (lane >> 4) ^ ((rl >> 1) & 3);
  for (int kt = 0; kt < nt; ++kt) {
    if (kt < nt - 2)       asm volatile("s_waitcnt vmcnt(8)" ::: "memory");
    else if (kt == nt - 2) asm volatile("s_waitcnt vmcnt(4)" ::: "memory");
    else                   asm volatile("s_waitcnt vmcnt(0)" ::: "memory");
    __builtin_amdgcn_s_barrier();
    const int buf = kt & 3;
    const _Float16* Ab  = &Al[buf][(wm * 64 + rl) * 32 + ca * 8];
    const _Float16* Bab = &Ba[buf][(wn * 32 + rl) * 32 + ca * 8];
    const _Float16* Bvb = &Bv[buf][(wn * 32 + rl) * 32 + ca * 8];
    half8 af[4], bfa[2], bfv[2];
#pragma unroll
    for (int i = 0; i < 4; i++) af[i] = *(const half8*)(Ab + i * 512);
#pragma unroll
    for (int j = 0; j < 2; j++) {
      bfa[j] = *(const half8*)(Bab + j * 512);
      bfv[j] = *(const half8*)(Bvb + j * 512);
    }
#pragma unroll
    for (int i = 0; i < 4; i++)
#pragma unroll
      for (int j = 0; j < 2; j++) {
        aca[i][j] = __builtin_amdgcn_mfma_f32_16x16x32_f16(af[i], bfa[j],
                                                           aca[i][j], 0, 0, 0);
        acv[i][j] = __builtin_amdgcn_mfma_f32_16x16x32_f16(af[i], bfv[j],
                                                           acv[i][j], 0, 0, 0);
      }
    if (kt + 3 < nt) STAGE((kt + 3) & 3, kt + 3);
  }
#undef STAGE

  const int rb = bm * 128 + wm * 64 + ((lane >> 4) << 2);
  const int cb = bn * 64 + wn * 32 + (lane & 15);
#pragma unroll
  for (int i = 0; i < 4; i++) {
#pragma unroll
    for (int j = 0; j < 2; j++) {
      int col = cb + j * 16;
#pragma unroll
      for (int q = 0; q < 4; q++) {
        int row = rb + i * 16 + q;
        if (row >= M) continue;
        float a = aca[i][j][q];
        float v = acv[i][j][q];
        Gh[(size_t)row * HID_ + col] = (_Float16)((a / (1.f + expf(-a))) * v);
      }
    }
  }
}

// ---------------------------------------------------------------------------
// fp16 MFMA GEMM, BM=64 BN=64, 4-deep pipeline, C-row-remap + optional fused
// positional encoding. Waves 2x2 of 32x32. LDS 32KB.
// ---------------------------------------------------------------------------
__global__ __launch_bounds__(256) void gemm16b_kernel(
    const _Float16* __restrict__ A, const _Float16* __restrict__ W,
    float* __restrict__ C, const float* __restrict__ bias,
    int M, int N, int K, int mode, int crpb, int cR, int cbase, int pe) {
  __shared__ _Float16 Al[4][2048];
  __shared__ _Float16 Bl[4][2048];

  const int t = threadIdx.x;
  const int nbm = (M + 63) >> 6;
  const int nwg = gridDim.x;
  int bid = blockIdx.x;
  if ((nwg & 7) == 0) {
    int q = nwg >> 3;
    bid = (bid & 7) * q + (bid >> 3);
  }
  const int bm = bid % nbm, bn = bid / nbm;
  const int lane = t & 63;
  const int w = t >> 6;
  const int wm = w >> 1, wn = w & 1;

  const int r0 = t >> 2;
  const int cp = t & 3;
  const int gc = cp ^ ((r0 >> 1) & 3);
  int gr = bm * 64 + r0;    if (gr >= M) gr = M - 1;
  int gcol = bn * 64 + r0;  if (gcol >= N) gcol = N - 1;
  const _Float16* pA = A + (size_t)gr * K + gc * 8;
  const _Float16* pB = W + (size_t)gcol * K + gc * 8;

#define STAGE(buf, kt)                                                         \
  do {                                                                         \
    ASYNC16(&Al[buf][t * 8], pA + (size_t)(kt) * 32);                          \
    ASYNC16(&Bl[buf][t * 8], pB + (size_t)(kt) * 32);                          \
  } while (0)

  f32x4 acc[2][2];
#pragma unroll
  for (int i = 0; i < 2; i++)
#pragma unroll
    for (int j = 0; j < 2; j++) acc[i][j] = (f32x4){0.f, 0.f, 0.f, 0.f};

  const int nt = K >> 5;  // >= 4 at all call sites
  STAGE(0, 0); STAGE(1, 1); STAGE(2, 2);

  const int rl = lane & 15;
  const int ca = (lane >> 4) ^ ((rl >> 1) & 3);
  for (int kt = 0; kt < nt; ++kt) {
    if (kt < nt - 2)       asm volatile("s_waitcnt vmcnt(4)" ::: "memory");
    else if (kt == nt - 2) asm volatile("s_waitcnt vmcnt(2)" ::: "memory");
    else                   asm volatile("s_waitcnt vmcnt(0)" ::: "memory");
    __builtin_amdgcn_s_barrier();
    const int buf = kt & 3;
    half8 af[2], bf[2];
#pragma unroll
    for (int i = 0; i < 2; i++)
      af[i] = *(const half8*)&Al[buf][(wm * 32 + i * 16 + rl) * 32 + ca * 8];
#pragma unroll
    for (int j = 0; j < 2; j++)
      bf[j] = *(const half8*)&Bl[buf][(wn * 32 + j * 16 + rl) * 32 + ca * 8];
#pragma unroll
    for (int i = 0; i < 2; i++)
#pragma unroll
      for (int j = 0; j < 2; j++)
        acc[i][j] = __builtin_amdgcn_mfma_f32_16x16x32_f16(af[i], bf[j],
                                                           acc[i][j], 0, 0, 0);
    if (kt + 3 < nt) STAGE((kt + 3) & 3, kt + 3);
  }
#undef STAGE

  const float PEK = -0.02703623196464017f;  // -2*ln(1000)/511
  const int rb = bm * 64 + wm * 32 + ((lane >> 4) << 2);
  const int cb = bn * 64 + wn * 32 + (lane & 15);
#pragma unroll
  for (int i = 0; i < 2; i++) {
#pragma unroll
    for (int j = 0; j < 2; j++) {
      int col = cb + j * 16;
      if (col >= N) continue;
#pragma unroll
      for (int q = 0; q < 4; q++) {
        int row = rb + i * 16 + q;
        if (row >= M) continue;
        int crow = (row / crpb) * cR + cbase + row % crpb;
        size_t idx = (size_t)crow * N + col;
        float v = acc[i][j][q];
        if (pe) {
          float pos = (float)(row % crpb);
          float ang = pos * expf((float)col * PEK);
          v += (col & 1) ? cosf(ang) : sinf(ang);
        }
        if (mode == MODE_STORE) C[idx] = v;
        else {
          float bb = bias ? bias[col] : 0.f;
          C[idx] = C[idx] + v + bb;
        }
      }
    }
  }
}

// ---------------------------------------------------------------------------
// Output head: out[m,c] = mask[m] ? x[m,c] :
//   x[m,c] + (A@Wv^T) * sigmoid(A@Wg^T + gb[c]).  N=256, BM=64, dual-B.
// ---------------------------------------------------------------------------
__global__ __launch_bounds__(256) void gemm16gate_kernel(
    const _Float16* __restrict__ A, const _Float16* __restrict__ Wv,
    const _Float16* __restrict__ Wg, const float* __restrict__ x,
    const float* __restrict__ gb, const int* __restrict__ mask,
    float* __restrict__ out, int M, int K, int arpb, int aR, int abase) {
  __shared__ _Float16 Al[4][2048];
  __shared__ _Float16 Bva[4][2048];
  __shared__ _Float16 Bga[4][2048];

  const int t = threadIdx.x;
  const int nbm = (M + 63) >> 6;
  const int nwg = gridDim.x;
  int bid = blockIdx.x;
  if ((nwg & 7) == 0) {
    int q = nwg >> 3;
    bid = (bid & 7) * q + (bid >> 3);
  }
  const int bm = bid % nbm, bn = bid / nbm;
  const int lane = t & 63;
  const int w = t >> 6;
  const int wm = w >> 1, wn = w & 1;

  const int r0 = t >> 2;
  const int cp = t & 3;
  const int gc = cp ^ ((r0 >> 1) & 3);
  int gr = bm * 64 + r0;  if (gr >= M) gr = M - 1;
  int ar = (gr / arpb) * aR + abase + gr % arpb;
  const int gcol = bn * 64 + r0;  // N=256 exact
  const _Float16* pA  = A + (size_t)ar * K + gc * 8;
  const _Float16* pBv = Wv + (size_t)gcol * K + gc * 8;
  const _Float16* pBg = Wg + (size_t)gcol * K + gc * 8;

#define STAGE(buf, kt)                                                         \
  do {                                                                         \
    ASYNC16(&Al[buf][t * 8], pA + (size_t)(kt) * 32);                          \
    ASYNC16(&Bva[buf][t * 8], pBv + (size_t)(kt) * 32);                        \
    ASYNC16(&Bga[buf][t * 8], pBg + (size_t)(kt) * 32);                        \
  } while (0)

  f32x4 acv[2][2], acg[2][2];
#pragma unroll
  for (int i = 0; i < 2; i++)
#pragma unroll
    for (int j = 0; j < 2; j++) {
      acv[i][j] = (f32x4){0.f, 0.f, 0.f, 0.f};
      acg[i][j] = (f32x4){0.f, 0.f, 0.f, 0.f};
    }

  const int nt = K >> 5;  // 16
  STAGE(0, 0); STAGE(1, 1); STAGE(2, 2);

  const int rl = lane & 15;
  const int ca = (lane >> 4) ^ ((rl >> 1) & 3);
  for (int kt = 0; kt < nt; ++kt) {
    if (kt < nt - 2)       asm volatile("s_waitcnt vmcnt(6)" ::: "memory");
    else if (kt == nt - 2) asm volatile("s_waitcnt vmcnt(3)" ::: "memory");
    else                   asm volatile("s_waitcnt vmcnt(0)" ::: "memory");
    __builtin_amdgcn_s_barrier();
    const int buf = kt & 3;
    half8 af[2], bv[2], bg2[2];
#pragma unroll
    for (int i = 0; i < 2; i++)
      af[i] = *(const half8*)&Al[buf][(wm * 32 + i * 16 + rl) * 32 + ca * 8];
#pragma unroll
    for (int j = 0; j < 2; j++) {
      bv[j] = *(const half8*)&Bva[buf][(wn * 32 + j * 16 + rl) * 32 + ca * 8];
      bg2[j] = *(const half8*)&Bga[buf][(wn * 32 + j * 16 + rl) * 32 + ca * 8];
    }
#pragma unroll
    for (int i = 0; i < 2; i++)
#pragma unroll
      for (int j = 0; j < 2; j++) {
        acv[i][j] = __builtin_amdgcn_mfma_f32_16x16x32_f16(af[i], bv[j],
                                                           acv[i][j], 0, 0, 0);
        acg[i][j] = __builtin_amdgcn_mfma_f32_16x16x32_f16(af[i], bg2[j],
                                                           acg[i][j], 0, 0, 0);
      }
    if (kt + 3 < nt) STAGE((kt + 3) & 3, kt + 3);
  }
#undef STAGE

  const int rb = bm * 64 + wm * 32 + ((lane >> 4) << 2);
  const int cb = bn * 64 + wn * 32 + (lane & 15);
#pragma unroll
  for (int i = 0; i < 2; i++) {
#pragma unroll
    for (int j = 0; j < 2; j++) {
      int col = cb + j * 16;
#pragma unroll
      for (int q = 0; q < 4; q++) {
        int row = rb + i * 16 + q;
        if (row >= M) continue;
        size_t idx = (size_t)row * DIN_ + col;
        float xv = x[idx];
        float res;
        if (mask[row]) {
          res = xv;
        } else {
          float gate = 1.f / (1.f + expf(-(acg[i][j][q] + gb[col])));
          res = xv + acv[i][j][q] * gate;
        }
        out[idx] = res;
      }
    }
  }
}

// ---------------------------------------------------------------------------
// LayerNorm: one block per row of 512; fp32 math, fp16 output
// ---------------------------------------------------------------------------
__global__ __launch_bounds__(256) void ln_kernel(
    const float* __restrict__ x, const float* __restrict__ g,
    const float* __restrict__ b, _Float16* __restrict__ out) {
  const int row = blockIdx.x;
  const int t = threadIdx.x;
  const float* xr = x + (size_t)row * D_;
  float v0 = xr[t], v1 = xr[t + 256];
  float s = v0 + v1, s2 = v0 * v0 + v1 * v1;
#pragma unroll
  for (int o = 32; o > 0; o >>= 1) {
    s += __shfl_down(s, o);
    s2 += __shfl_down(s2, o);
  }
  __shared__ float w1[4], w2[4], mv[2];
  const int w = t >> 6;
  if ((t & 63) == 0) { w1[w] = s; w2[w] = s2; }
  __syncthreads();
  if (t == 0) {
    float ss = w1[0] + w1[1] + w1[2] + w1[3];
    float ss2 = w2[0] + w2[1] + w2[2] + w2[3];
    float mean = ss * (1.f / D_);
    float var = ss2 * (1.f / D_) - mean * mean;
    mv[0] = mean;
    mv[1] = rsqrtf(var + 1e-5f);
  }
  __syncthreads();
  float mean = mv[0], inv = mv[1];
  _Float16* orow = out + (size_t)row * D_;
  orow[t] = (_Float16)((v0 - mean) * inv * g[t] + b[t]);
  orow[t + 256] = (_Float16)((v1 - mean) * inv * g[t + 256] + b[t + 256]);
}

// ---------------------------------------------------------------------------
// Multi-segment fp32 -> fp16 (13 segments), grid-stride over 8-elem units
// ---------------------------------------------------------------------------
struct ThSegs {
  const float* src[13];
  _Float16* dst[13];
  int cum[14];  // cumulative n8
};
__global__ void tohalf_multi_kernel(ThSegs sg) {
  int total = sg.cum[13];
  for (int i = blockIdx.x * blockDim.x + threadIdx.x; i < total;
       i += gridDim.x * blockDim.x) {
    int s = 0;
    while (i >= sg.cum[s + 1]) s++;
    int off = i - sg.cum[s];
    const float4* p = (const float4*)(sg.src[s] + (size_t)off * 8);
    float4 x = p[0], y = p[1];
    half8 h = {(_Float16)x.x, (_Float16)x.y, (_Float16)x.z, (_Float16)x.w,
               (_Float16)y.x, (_Float16)y.y, (_Float16)y.z, (_Float16)y.w};
    *(half8*)(sg.dst[s] + (size_t)off * 8) = h;
  }
}

__global__ void tohalf_kernel(const float* __restrict__ src,
                              _Float16* __restrict__ dst, int n8) {
  for (int i = blockIdx.x * blockDim.x + threadIdx.x; i < n8;
       i += gridDim.x * blockDim.x) {
    const float4* s = (const float4*)(src + (size_t)i * 8);
    float4 x = s[0], y = s[1];
    half8 h = {(_Float16)x.x, (_Float16)x.y, (_Float16)x.z, (_Float16)x.w,
               (_Float16)y.x, (_Float16)y.y, (_Float16)y.z, (_Float16)y.w};
    *(half8*)(dst + (size_t)i * 8) = h;
  }
}

// ---------------------------------------------------------------------------
// prep: concat rots/trans/mask + padded mask + zero K/V pad columns
// ---------------------------------------------------------------------------
__global__ void prep_kernel(
    const float* __restrict__ vh_rots, const float* __restrict__ vh_trans,
    const float* __restrict__ vl_rots, const float* __restrict__ vl_trans,
    const float* __restrict__ ep_rots, const float* __restrict__ ep_trans,
    const int* __restrict__ vh_mask, const int* __restrict__ vl_mask,
    const int* __restrict__ ep_mask, float* __restrict__ rots,
    float* __restrict__ trans, int* __restrict__ mask,
    int* __restrict__ maskp, float* __restrict__ Kt, float* __restrict__ PKt,
    float* __restrict__ Vt) {
  int idx = blockIdx.x * blockDim.x + threadIdx.x;
  if (idx < B_ * RP_) {
    int b = idx >> 9, r = idx & (RP_ - 1);
    if (r >= R_) {
      maskp[idx] = 1;
      return;
    }
    const float* sr; const float* st; int sm;
    if (r < VH_) {
      sr = vh_rots + (size_t)(b * VH_ + r) * 9;
      st = vh_trans + (size_t)(b * VH_ + r) * 3;
      sm = vh_mask[b * VH_ + r];
    } else if (r < VH_ + VL_) {
      int rr = r - VH_;
      sr = vl_rots + (size_t)(b * VL_ + rr) * 9;
      st = vl_trans + (size_t)(b * VL_ + rr) * 3;
      sm = vl_mask[b * VL_ + rr];
    } else {
      int rr = r - VH_ - VL_;
      sr = ep_rots + (size_t)(b * EP_ + rr) * 9;
      st = ep_trans + (size_t)(b * EP_ + rr) * 3;
      sm = ep_mask[b * EP_ + rr];
    }
    int lin = b * R_ + r;
    maskp[idx] = sm;
    mask[lin] = sm;
#pragma unroll
    for (int k = 0; k < 9; k++) rots[(size_t)lin * 9 + k] = sr[k];
#pragma unroll
    for (int k = 0; k < 3; k++) trans[(size_t)lin * 3 + k] = st[k];
  } else {
    int p = idx - B_ * RP_;
    const int per = B_ * H_ * 3 * (RP_ - R_);
    if (p >= 3 * per) return;
    int a = p / per;
    int q = p % per;
    int chan = q / (RP_ - R_), jj = q % (RP_ - R_);
    float* dst = (a == 0) ? Kt : (a == 1) ? PKt : Vt;
    dst[(size_t)chan * RP_ + R_ + jj] = 0.f;
  }
}

// ---------------------------------------------------------------------------
// Rotate QKV fields; Q-side row-major, K/V-side transposed [b][h][3][j]
// ---------------------------------------------------------------------------
__global__ __launch_bounds__(128) void rotate_kernel(
    const float* __restrict__ qkv_raw, const float* __restrict__ rots,
    const float* __restrict__ trans, float* __restrict__ Qrow,
    float* __restrict__ PQrow, float* __restrict__ Kt,
    float* __restrict__ PKt, float* __restrict__ Vt) {
  const int blk = blockIdx.x;
  const int b = blk / R_;
  const int r = blk % R_;
  const int t = threadIdx.x;
  __shared__ float Rm[9], tr[3], raw[240];
  if (t < 9) Rm[t] = rots[(size_t)blk * 9 + t];
  if (t >= 9 && t < 12) tr[t - 9] = trans[(size_t)blk * 3 + (t - 9)];
  for (int i = t; i < 240; i += 128) raw[i] = qkv_raw[(size_t)blk * 240 + i];
  __syncthreads();
  if (t < 80) {
    int f = t / 16, h = t % 16;
    float x = raw[f * 48 + h * 3 + 0];
    float y = raw[f * 48 + h * 3 + 1];
    float z = raw[f * 48 + h * 3 + 2];
    float r0 = Rm[0] * x + Rm[1] * y + Rm[2] * z;
    float r1 = Rm[3] * x + Rm[4] * y + Rm[5] * z;
    float r2 = Rm[6] * x + Rm[7] * y + Rm[8] * z;
    if (f == 2 || f == 3) { r0 += tr[0]; r1 += tr[1]; r2 += tr[2]; }
    if (f == 0 || f == 2) {
      float* dst = (f == 0) ? Qrow : PQrow;
      size_t o = (size_t)blk * 48 + h * 3;
      dst[o] = r0; dst[o + 1] = r1; dst[o + 2] = r2;
    } else {
      float* dst = (f == 1) ? Kt : (f == 3) ? PKt : Vt;
      size_t base = ((size_t)(b * H_ + h) * 3) * RP_ + r;
      dst[base] = r0; dst[base + RP_] = r1; dst[base + 2 * RP_] = r2;
    }
  }
}

// ---------------------------------------------------------------------------
// Attention: block per (b, i-pair); fused inverse-rotation + out-projection
// (emb[row] += out_b + out_w(512x48) @ o_rot).
// ---------------------------------------------------------------------------
__global__ __launch_bounds__(256) void attn2_kernel(
    const float* __restrict__ Qrow, const float* __restrict__ PQrow,
    const float* __restrict__ Kt, const float* __restrict__ PKt,
    const float* __restrict__ Vt, const float* __restrict__ rots,
    const int* __restrict__ mask, const int* __restrict__ maskp,
    const float* __restrict__ rs, const float* __restrict__ ds,
    const float* __restrict__ out_w, const float* __restrict__ out_b,
    float* __restrict__ emb) {
  const int blk = blockIdx.x;
  const int b = blk / (R_ / 2);
  const int ip = blk % (R_ / 2);
  const int i0 = ip * 2;
  const int t = threadIdx.x;
  const int lane = t & 63;
  const int w = t >> 6;

  __shared__ float qs[2][48], ps[2][48], og[2][48];
  __shared__ float crs[16], cds[16];
  __shared__ int mi[2];

  if (t < 96) {
    int io = t / 48, k2 = t % 48;
    int i = i0 + io;
    qs[io][k2] = Qrow[((size_t)(b * R_ + i)) * 48 + k2];
    ps[io][k2] = PQrow[((size_t)(b * R_ + i)) * 48 + k2];
  } else if (t < 112) {
    int h = t - 96;
    const float sc = 0.57735026918962576f;
    crs[h] = log1pf(expf(rs[h])) * sc;
    cds[h] = log1pf(expf(ds[h])) * sc;
  } else if (t < 114) {
    mi[t - 112] = mask[b * R_ + i0 + (t - 112)];
  }
  __syncthreads();

  float mb[8];
#pragma unroll
  for (int jb = 0; jb < 8; jb++) {
    int j = jb * 64 + lane;
    mb[jb] = maskp[b * RP_ + j] ? -1e9f : 0.f;
  }
  const float bi0 = mi[0] ? -1e9f : 0.f;
  const float bi1 = mi[1] ? -1e9f : 0.f;

  for (int hh = 0; hh < 4; hh++) {
    const int h = hh * 4 + w;
    const float sA = crs[h], sD = cds[h];
    const float qx0 = qs[0][h * 3], qy0 = qs[0][h * 3 + 1], qz0 = qs[0][h * 3 + 2];
    const float px0 = ps[0][h * 3], py0 = ps[0][h * 3 + 1], pz0 = ps[0][h * 3 + 2];
    const float qx1 = qs[1][h * 3], qy1 = qs[1][h * 3 + 1], qz1 = qs[1][h * 3 + 2];
    const float px1 = ps[1][h * 3], py1 = ps[1][h * 3 + 1], pz1 = ps[1][h * 3 + 2];
    const float* kb = Kt + ((size_t)(b * H_ + h) * 3) * RP_;
    const float* pb = PKt + ((size_t)(b * H_ + h) * 3) * RP_;
    const float* vb = Vt + ((size_t)(b * H_ + h) * 3) * RP_;

    float l0[8], l1[8];
    float m0 = -3e38f, m1 = -3e38f;
#pragma unroll
    for (int jb = 0; jb < 8; jb++) {
      int j = jb * 64 + lane;
      float kx = kb[j], ky = kb[j + RP_], kz = kb[j + 2 * RP_];
      float pkx = pb[j], pky = pb[j + RP_], pkz = pb[j + 2 * RP_];
      float dx0 = px0 - pkx, dy0 = py0 - pky, dz0 = pz0 - pkz;
      float d0 = sqrtf(dx0 * dx0 + dy0 * dy0 + dz0 * dz0);
      l0[jb] = (qx0 * kx + qy0 * ky + qz0 * kz) * sA - d0 * sD + mb[jb] + bi0;
      m0 = fmaxf(m0, l0[jb]);
      float dx1 = px1 - pkx, dy1 = py1 - pky, dz1 = pz1 - pkz;
      float d1 = sqrtf(dx1 * dx1 + dy1 * dy1 + dz1 * dz1);
      l1[jb] = (qx1 * kx + qy1 * ky + qz1 * kz) * sA - d1 * sD + mb[jb] + bi1;
      m1 = fmaxf(m1, l1[jb]);
    }
#pragma unroll
    for (int s = 1; s < 64; s <<= 1) {
      m0 = fmaxf(m0, __shfl_xor(m0, s));
      m1 = fmaxf(m1, __shfl_xor(m1, s));
    }
    float s0 = 0.f, s1 = 0.f;
    float ox0 = 0.f, oy0 = 0.f, oz0 = 0.f, ox1 = 0.f, oy1 = 0.f, oz1 = 0.f;
#pragma unroll
    for (int jb = 0; jb < 8; jb++) {
      int j = jb * 64 + lane;
      float p0 = expf(l0[jb] - m0);
      float p1 = expf(l1[jb] - m1);
      s0 += p0; s1 += p1;
      float vx = vb[j], vy = vb[j + RP_], vz = vb[j + 2 * RP_];
      ox0 += p0 * vx; oy0 += p0 * vy; oz0 += p0 * vz;
      ox1 += p1 * vx; oy1 += p1 * vy; oz1 += p1 * vz;
    }
#pragma unroll
    for (int s = 1; s < 64; s <<= 1) {
      s0 += __shfl_xor(s0, s); s1 += __shfl_xor(s1, s);
      ox0 += __shfl_xor(ox0, s); oy0 += __shfl_xor(oy0, s); oz0 += __shfl_xor(oz0, s);
      ox1 += __shfl_xor(ox1, s); oy1 += __shfl_xor(oy1, s); oz1 += __shfl_xor(oz1, s);
    }
    if (lane == 0) {
      og[0][h * 3] = ox0 / s0; og[0][h * 3 + 1] = oy0 / s0; og[0][h * 3 + 2] = oz0 / s0;
      og[1][h * 3] = ox1 / s1; og[1][h * 3 + 1] = oy1 / s1; og[1][h * 3 + 2] = oz1 / s1;
    }
  }
  __syncthreads();
  // inverse rotation in-place on og
  float r0v0 = 0.f, r0v1 = 0.f;
  if (t < 48) {
    int h = t / 3, i3 = t % 3;
    const float* Rm0 = rots + ((size_t)(b * R_ + i0)) * 9;
    const float* Rm1 = rots + ((size_t)(b * R_ + i0 + 1)) * 9;
    r0v0 = Rm0[0 + i3] * og[0][h * 3 + 0] + Rm0[3 + i3] * og[0][h * 3 + 1] +
           Rm0[6 + i3] * og[0][h * 3 + 2];
    r0v1 = Rm1[0 + i3] * og[1][h * 3 + 0] + Rm1[3 + i3] * og[1][h * 3 + 1] +
           Rm1[6 + i3] * og[1][h * 3 + 2];
  }
  __syncthreads();
  if (t < 48) { og[0][t] = r0v0; og[1][t] = r0v1; }
  __syncthreads();
  // fused out-projection
#pragma unroll
  for (int io = 0; io < 2; io++) {
    float* erow = emb + ((size_t)(b * R_ + i0 + io)) * D_;
#pragma unroll
    for (int half = 0; half < 2; half++) {
      int c = half * 256 + t;
      const float* wr = out_w + (size_t)c * 48;
      float s = out_b[c];
#pragma unroll
      for (int k = 0; k < 48; k++) s += og[io][k] * wr[k];
      erow[c] += s;
    }
  }
}

// ---------------------------------------------------------------------------
extern "C" void kernel_launch(void* const* d_in, const int* in_sizes, int n_in,
                              void* d_out, int out_size, void* d_ws, size_t ws_size,
                              hipStream_t stream) {
  const float* vh_x = (const float*)d_in[0];
  const float* vl_x = (const float*)d_in[1];
  const float* vh_rots = (const float*)d_in[2];
  const float* vh_trans = (const float*)d_in[3];
  const float* vl_rots = (const float*)d_in[4];
  const float* vl_trans = (const float*)d_in[5];
  const float* ep_feats = (const float*)d_in[6];
  const float* ep_rots = (const float*)d_in[7];
  const float* ep_trans = (const float*)d_in[8];
  const int* vh_mask = (const int*)d_in[9];
  const int* vl_mask = (const int*)d_in[10];
  const int* ep_mask = (const int*)d_in[11];
  const float* vh_emb_w = (const float*)d_in[12];
  const float* vl_emb_w = (const float*)d_in[13];
  const float* tgt_emb_w = (const float*)d_in[14];
  const float* qkv_w = (const float*)d_in[15];
  const float* out_w = (const float*)d_in[16];
  const float* out_b = (const float*)d_in[17];
  const float* ln_g = (const float*)d_in[18];
  const float* ln_b = (const float*)d_in[19];
  const float* r_scale = (const float*)d_in[20];
  const float* d_scale = (const float*)d_in[21];
  const float* ln2_g = (const float*)d_in[22];
  const float* ln2_b = (const float*)d_in[23];
  const float* w12 = (const float*)d_in[24];
  const float* w3 = (const float*)d_in[25];
  const float* out_vh_w = (const float*)d_in[26];
  const float* out_vh_gate_w = (const float*)d_in[27];
  const float* out_vh_gate_b = (const float*)d_in[28];
  const float* out_vl_w = (const float*)d_in[29];
  const float* out_vl_gate_w = (const float*)d_in[30];
  const float* out_vl_gate_b = (const float*)d_in[31];

  const int BR = B_ * R_;  // 2024

  // ---- workspace layout (256B-aligned) ----
  uint8_t* P = (uint8_t*)d_ws;
  auto alloc = [&](size_t bytes) {
    uint8_t* p = P;
    P += (bytes + 255) & ~(size_t)255;
    return p;
  };
  float* emb = (float*)alloc((size_t)BR * D_ * 4);
  _Float16* xnh = (_Float16*)alloc((size_t)BR * D_ * 2);
  float* qkvr = (float*)alloc((size_t)BR * 240 * 4);
  float* Qrow = (float*)alloc((size_t)BR * 48 * 4);
  float* PQrow = (float*)alloc((size_t)BR * 48 * 4);
  float* Kt = (float*)alloc((size_t)B_ * H_ * 3 * RP_ * 4);
  float* PKt = (float*)alloc((size_t)B_ * H_ * 3 * RP_ * 4);
  float* Vt = (float*)alloc((size_t)B_ * H_ * 3 * RP_ * 4);
  _Float16* ghalf = (_Float16*)alloc((size_t)BR * HID_ * 2);
  float* rots_c = (float*)alloc((size_t)BR * 9 * 4);
  float* trans_c = (float*)alloc((size_t)BR * 3 * 4);
  int* mask_c = (int*)alloc((size_t)BR * 4);
  int* maskp = (int*)alloc((size_t)B_ * RP_ * 4);
  _Float16* embh = (_Float16*)alloc((size_t)BR * D_ * 2);
  _Float16* qkvh = (_Float16*)alloc((size_t)NL_ * 240 * D_ * 2);
  _Float16* w12h = (_Float16*)alloc((size_t)NL_ * 2 * HID_ * D_ * 2);
  _Float16* w3h = (_Float16*)alloc((size_t)NL_ * D_ * HID_ * 2);
  _Float16* vhxh = (_Float16*)alloc((size_t)B_ * VH_ * DIN_ * 2);
  _Float16* vlxh = (_Float16*)alloc((size_t)B_ * VL_ * DIN_ * 2);
  _Float16* eph = (_Float16*)alloc((size_t)B_ * EP_ * DEP_ * 2);
  _Float16* vhewh = (_Float16*)alloc((size_t)D_ * DIN_ * 2);
  _Float16* vlewh = (_Float16*)alloc((size_t)D_ * DIN_ * 2);
  _Float16* tgewh = (_Float16*)alloc((size_t)D_ * DEP_ * 2);
  _Float16* ovhw = (_Float16*)alloc((size_t)DIN_ * D_ * 2);
  _Float16* ovhgw = (_Float16*)alloc((size_t)DIN_ * D_ * 2);
  _Float16* ovlw = (_Float16*)alloc((size_t)DIN_ * D_ * 2);
  _Float16* ovlgw = (_Float16*)alloc((size_t)DIN_ * D_ * 2);

  // one multi-segment fp32->fp16 conversion (weights + inputs)
  {
    ThSegs sg;
    const float* srcs[13] = {qkv_w, w12, w3, vh_x, vl_x, ep_feats,
                             vh_emb_w, vl_emb_w, tgt_emb_w,
                             out_vh_w, out_vh_gate_w, out_vl_w, out_vl_gate_w};
    _Float16* dsts[13] = {qkvh, w12h, w3h, vhxh, vlxh, eph,
                          vhewh, vlewh, tgewh, ovhw, ovhgw, ovlw, ovlgw};
    int n8s[13] = {NL_ * 240 * D_ / 8, NL_ * 2 * HID_ * D_ / 8,
                   NL_ * D_ * HID_ / 8, B_ * VH_ * DIN_ / 8,
                   B_ * VL_ * DIN_ / 8, B_ * EP_ * DEP_ / 8,
                   D_ * DIN_ / 8, D_ * DIN_ / 8, D_ * DEP_ / 8,
                   DIN_ * D_ / 8, DIN_ * D_ / 8, DIN_ * D_ / 8, DIN_ * D_ / 8};
    int c = 0;
    for (int i = 0; i < 13; i++) {
      sg.src[i] = srcs[i]; sg.dst[i] = dsts[i];
      sg.cum[i] = c; c += n8s[i];
    }
    sg.cum[13] = c;
    tohalf_multi_kernel<<<2048, 256, 0, stream>>>(sg);
  }

  // prep: concat + padded mask + K/V pad zero
  {
    int total = B_ * RP_ + 3 * B_ * H_ * 3 * (RP_ - R_);
    prep_kernel<<<(total + 255) / 256, 256, 0, stream>>>(
        vh_rots, vh_trans, vl_rots, vl_trans, ep_rots, ep_trans, vh_mask,
        vl_mask, ep_mask, rots_c, trans_c, mask_c, maskp, Kt, PKt, Vt);
  }

  auto gemm16b = [&](const _Float16* A, const _Float16* W, float* C,
                     const float* bias, int M, int N, int K, int mode,
                     int crpb, int cR, int cbase, int pe) {
    int nbm = (M + 63) / 64, nbn = (N + 63) / 64;
    gemm16b_kernel<<<nbm * nbn, 256, 0, stream>>>(A, W, C, bias, M, N, K, mode,
                                                  crpb, cR, cbase, pe);
  };

  // embeddings (fp16 MFMA, fused PE, remapped into emb)
  gemm16b(vhxh, vhewh, emb, nullptr, B_ * VH_, D_, DIN_, MODE_STORE,
          VH_, R_, 0, 1);
  gemm16b(vlxh, vlewh, emb, nullptr, B_ * VL_, D_, DIN_, MODE_STORE,
          VL_, R_, VH_, 1);
  gemm16b(eph, tgewh, emb, nullptr, B_ * EP_, D_, DEP_, MODE_STORE,
          EP_, R_, VH_ + VL_, 0);

  for (int l = 0; l < NL_; l++) {
    const _Float16* qwh = qkvh + (size_t)l * 240 * D_;
    const float* ow = out_w + (size_t)l * D_ * 48;
    const float* obias = out_b + (size_t)l * D_;
    const float* lg = ln_g + (size_t)l * D_;
    const float* lb = ln_b + (size_t)l * D_;
    const float* l2g = ln2_g + (size_t)l * D_;
    const float* l2b = ln2_b + (size_t)l * D_;
    const float* rs = r_scale + (size_t)l * H_;
    const float* dsc = d_scale + (size_t)l * H_;
    const _Float16* w12ah = w12h + (size_t)l * 2 * HID_ * D_;
    const _Float16* w12bh = w12ah + (size_t)HID_ * D_;
    const _Float16* w3lh = w3h + (size_t)l * D_ * HID_;

    // attention (out-projection fused into attn2)
    ln_kernel<<<BR, 256, 0, stream>>>(emb, lg, lb, xnh);
    gemm16b(xnh, qwh, qkvr, nullptr, BR, 240, D_, MODE_STORE, BR, BR, 0, 0);
    rotate_kernel<<<BR, 128, 0, stream>>>(qkvr, rots_c, trans_c, Qrow, PQrow,
                                          Kt, PKt, Vt);
    attn2_kernel<<<B_ * (R_ / 2), 256, 0, stream>>>(
        Qrow, PQrow, Kt, PKt, Vt, rots_c, mask_c, maskp, rs, dsc, ow, obias,
        emb);

    // swiglu
    ln_kernel<<<BR, 256, 0, stream>>>(emb, l2g, l2b, xnh);
    {
      int nbm = (BR + 127) / 128, nbn = HID_ / 64;
      gemm16sw_kernel<<<nbm * nbn, 256, 0, stream>>>(xnh, w12ah, w12bh, ghalf,
                                                     BR, D_);
    }
    gemm16b(ghalf, w3lh, emb, nullptr, BR, D_, HID_, MODE_ADD_BIAS,
            BR, BR, 0, 0);
  }

  // output heads: emb -> fp16, then fused dual-GEMM + gate -> d_out
  tohalf_kernel<<<1024, 256, 0, stream>>>(emb, embh, BR * D_ / 8);
  {
    int M = B_ * VH_;
    int nbm = (M + 63) / 64;
    gemm16gate_kernel<<<nbm * 4, 256, 0, stream>>>(
        embh, ovhw, ovhgw, vh_x, out_vh_gate_b, vh_mask, (float*)d_out, M, D_,
        VH_, R_, 0);
  }
  {
    int M = B_ * VL_;
    int nbm = (M + 63) / 64;
    gemm16gate_kernel<<<nbm * 4, 256, 0, stream>>>(
        embh, ovlw, ovlgw, vl_x, out_vl_gate_b, vl_mask,
        (float*)d_out + (size_t)B_ * VH_ * DIN_, M, D_, VL_, R_, VH_);
  }
}

// Round 8
// 1108.081 us; speedup vs baseline: 3.6379x; 1.1841x over previous
//
#include <hip/hip_runtime.h>
#include <hip/hip_bf16.h>
#include <math.h>
#include <stdint.h>

// Problem constants
#define B_ 4
#define VH_ 130
#define VL_ 120
#define EP_ 256
#define R_ 506           // VH+VL+EP
#define RP_ 512          // padded R for transposed K/V layouts
#define DIN_ 256
#define DEP_ 128
#define D_ 512
#define H_ 16
#define NL_ 8
#define HID_ 2048

#define MODE_STORE 0
#define MODE_ADD_BIAS 1

typedef _Float16 half8 __attribute__((ext_vector_type(8)));
typedef float f32x4 __attribute__((ext_vector_type(4)));

// async global->LDS 16B copy (width literal)
#define ASYNC16(ldsdst, gsrc)                                                  \
  __builtin_amdgcn_global_load_lds(                                            \
      (const __attribute__((address_space(1))) unsigned int*)(gsrc),           \
      (__attribute__((address_space(3))) unsigned int*)(ldsdst), 16, 0, 0)

// ---------------------------------------------------------------------------
// fp16 MFMA GEMM, BM=128 BN=64, 4-deep pipeline, fused SwiGLU (dual-B).
// ghalf[m,n] = f16( silu(A@Wa^T) * (A@Wv^T) ), N=HID. (validated round 5)
// ---------------------------------------------------------------------------
__global__ __launch_bounds__(256) void gemm16sw_kernel(
    const _Float16* __restrict__ A, const _Float16* __restrict__ Wa,
    const _Float16* __restrict__ Wv, _Float16* __restrict__ Gh,
    int M, int K) {
  __shared__ _Float16 Al[4][4096];
  __shared__ _Float16 Ba[4][2048];
  __shared__ _Float16 Bv[4][2048];

  const int t = threadIdx.x;
  const int nbm = (M + 127) >> 7;
  const int nwg = gridDim.x;
  int bid = blockIdx.x;
  if ((nwg & 7) == 0) {
    int q = nwg >> 3;
    bid = (bid & 7) * q + (bid >> 3);
  }
  const int bm = bid % nbm, bn = bid / nbm;
  const int lane = t & 63;
  const int w = t >> 6;
  const int wm = w >> 1, wn = w & 1;

  const int r0 = t >> 2;
  const int cp = t & 3;
  const int gc = cp ^ ((r0 >> 1) & 3);
  int gr0 = bm * 128 + r0;       if (gr0 >= M) gr0 = M - 1;
  int gr1 = bm * 128 + 64 + r0;  if (gr1 >= M) gr1 = M - 1;
  const int gcol = bn * 64 + r0;  // N=2048 exact
  const _Float16* pA0 = A + (size_t)gr0 * K + gc * 8;
  const _Float16* pA1 = A + (size_t)gr1 * K + gc * 8;
  const _Float16* pBa = Wa + (size_t)gcol * K + gc * 8;
  const _Float16* pBv = Wv + (size_t)gcol * K + gc * 8;

#define STAGE(buf, kt)                                                         \
  do {                                                                         \
    ASYNC16(&Al[buf][t * 8], pA0 + (size_t)(kt) * 32);                         \
    ASYNC16(&Al[buf][2048 + t * 8], pA1 + (size_t)(kt) * 32);                  \
    ASYNC16(&Ba[buf][t * 8], pBa + (size_t)(kt) * 32);                         \
    ASYNC16(&Bv[buf][t * 8], pBv + (size_t)(kt) * 32);                         \
  } while (0)

  f32x4 aca[4][2], acv[4][2];
#pragma unroll
  for (int i = 0; i < 4; i++)
#pragma unroll
    for (int j = 0; j < 2; j++) {
      aca[i][j] = (f32x4){0.f, 0.f, 0.f, 0.f};
      acv[i][j] = (f32x4){0.f, 0.f, 0.f, 0.f};
    }

  const int nt = K >> 5;
  STAGE(0, 0); STAGE(1, 1); STAGE(2, 2);

  const int rl = lane & 15;
  const int ca = (lane >> 4) ^ ((rl >> 1) & 3);
  for (int kt = 0; kt < nt; ++kt) {
    if (kt < nt - 2)       asm volatile("s_waitcnt vmcnt(8)" ::: "memory");
    else if (kt == nt - 2) asm volatile("s_waitcnt vmcnt(4)" ::: "memory");
    else                   asm volatile("s_waitcnt vmcnt(0)" ::: "memory");
    __builtin_amdgcn_s_barrier();
    const int buf = kt & 3;
    const _Float16* Ab  = &Al[buf][(wm * 64 + rl) * 32 + ca * 8];
    const _Float16* Bab = &Ba[buf][(wn * 32 + rl) * 32 + ca * 8];
    const _Float16* Bvb = &Bv[buf][(wn * 32 + rl) * 32 + ca * 8];
    half8 af[4], bfa[2], bfv[2];
#pragma unroll
    for (int i = 0; i < 4; i++) af[i] = *(const half8*)(Ab + i * 512);
#pragma unroll
    for (int j = 0; j < 2; j++) {
      bfa[j] = *(const half8*)(Bab + j * 512);
      bfv[j] = *(const half8*)(Bvb + j * 512);
    }
#pragma unroll
    for (int i = 0; i < 4; i++)
#pragma unroll
      for (int j = 0; j < 2; j++) {
        aca[i][j] = __builtin_amdgcn_mfma_f32_16x16x32_f16(af[i], bfa[j],
                                                           aca[i][j], 0, 0, 0);
        acv[i][j] = __builtin_amdgcn_mfma_f32_16x16x32_f16(af[i], bfv[j],
                                                           acv[i][j], 0, 0, 0);
      }
    if (kt + 3 < nt) STAGE((kt + 3) & 3, kt + 3);
  }
#undef STAGE

  const int rb = bm * 128 + wm * 64 + ((lane >> 4) << 2);
  const int cb = bn * 64 + wn * 32 + (lane & 15);
#pragma unroll
  for (int i = 0; i < 4; i++) {
#pragma unroll
    for (int j = 0; j < 2; j++) {
      int col = cb + j * 16;
#pragma unroll
      for (int q = 0; q < 4; q++) {
        int row = rb + i * 16 + q;
        if (row >= M) continue;
        float a = aca[i][j][q];
        float v = acv[i][j][q];
        Gh[(size_t)row * HID_ + col] = (_Float16)((a / (1.f + expf(-a))) * v);
      }
    }
  }
}

// ---------------------------------------------------------------------------
// fp16 MFMA GEMM, BM=64 BN=64, 4-deep pipeline, C-row-remap + optional fused
// positional encoding. Waves 2x2 of 32x32. LDS 32KB.
// ---------------------------------------------------------------------------
__global__ __launch_bounds__(256) void gemm16b_kernel(
    const _Float16* __restrict__ A, const _Float16* __restrict__ W,
    float* __restrict__ C, const float* __restrict__ bias,
    int M, int N, int K, int mode, int crpb, int cR, int cbase, int pe) {
  __shared__ _Float16 Al[4][2048];
  __shared__ _Float16 Bl[4][2048];

  const int t = threadIdx.x;
  const int nbm = (M + 63) >> 6;
  const int nwg = gridDim.x;
  int bid = blockIdx.x;
  if ((nwg & 7) == 0) {
    int q = nwg >> 3;
    bid = (bid & 7) * q + (bid >> 3);
  }
  const int bm = bid % nbm, bn = bid / nbm;
  const int lane = t & 63;
  const int w = t >> 6;
  const int wm = w >> 1, wn = w & 1;

  const int r0 = t >> 2;
  const int cp = t & 3;
  const int gc = cp ^ ((r0 >> 1) & 3);
  int gr = bm * 64 + r0;    if (gr >= M) gr = M - 1;
  int gcol = bn * 64 + r0;  if (gcol >= N) gcol = N - 1;
  const _Float16* pA = A + (size_t)gr * K + gc * 8;
  const _Float16* pB = W + (size_t)gcol * K + gc * 8;

#define STAGE(buf, kt)                                                         \
  do {                                                                         \
    ASYNC16(&Al[buf][t * 8], pA + (size_t)(kt) * 32);                          \
    ASYNC16(&Bl[buf][t * 8], pB + (size_t)(kt) * 32);                          \
  } while (0)

  f32x4 acc[2][2];
#pragma unroll
  for (int i = 0; i < 2; i++)
#pragma unroll
    for (int j = 0; j < 2; j++) acc[i][j] = (f32x4){0.f, 0.f, 0.f, 0.f};

  const int nt = K >> 5;  // >= 4 at all call sites
  STAGE(0, 0); STAGE(1, 1); STAGE(2, 2);

  const int rl = lane & 15;
  const int ca = (lane >> 4) ^ ((rl >> 1) & 3);
  for (int kt = 0; kt < nt; ++kt) {
    if (kt < nt - 2)       asm volatile("s_waitcnt vmcnt(4)" ::: "memory");
    else if (kt == nt - 2) asm volatile("s_waitcnt vmcnt(2)" ::: "memory");
    else                   asm volatile("s_waitcnt vmcnt(0)" ::: "memory");
    __builtin_amdgcn_s_barrier();
    const int buf = kt & 3;
    half8 af[2], bf[2];
#pragma unroll
    for (int i = 0; i < 2; i++)
      af[i] = *(const half8*)&Al[buf][(wm * 32 + i * 16 + rl) * 32 + ca * 8];
#pragma unroll
    for (int j = 0; j < 2; j++)
      bf[j] = *(const half8*)&Bl[buf][(wn * 32 + j * 16 + rl) * 32 + ca * 8];
#pragma unroll
    for (int i = 0; i < 2; i++)
#pragma unroll
      for (int j = 0; j < 2; j++)
        acc[i][j] = __builtin_amdgcn_mfma_f32_16x16x32_f16(af[i], bf[j],
                                                           acc[i][j], 0, 0, 0);
    if (kt + 3 < nt) STAGE((kt + 3) & 3, kt + 3);
  }
#undef STAGE

  const float PEK = -0.02703623196464017f;  // -2*ln(1000)/511
  const int rb = bm * 64 + wm * 32 + ((lane >> 4) << 2);
  const int cb = bn * 64 + wn * 32 + (lane & 15);
#pragma unroll
  for (int i = 0; i < 2; i++) {
#pragma unroll
    for (int j = 0; j < 2; j++) {
      int col = cb + j * 16;
      if (col >= N) continue;
#pragma unroll
      for (int q = 0; q < 4; q++) {
        int row = rb + i * 16 + q;
        if (row >= M) continue;
        int crow = (row / crpb) * cR + cbase + row % crpb;
        size_t idx = (size_t)crow * N + col;
        float v = acc[i][j][q];
        if (pe) {
          float pos = (float)(row % crpb);
          float ang = pos * expf((float)col * PEK);
          v += (col & 1) ? cosf(ang) : sinf(ang);
        }
        if (mode == MODE_STORE) C[idx] = v;
        else {
          float bb = bias ? bias[col] : 0.f;
          C[idx] = C[idx] + v + bb;
        }
      }
    }
  }
}

// ---------------------------------------------------------------------------
// Output head: out[m,c] = mask[m] ? x[m,c] :
//   x[m,c] + (A@Wv^T) * sigmoid(A@Wg^T + gb[c]).  N=256, BM=64, dual-B.
// ---------------------------------------------------------------------------
__global__ __launch_bounds__(256) void gemm16gate_kernel(
    const _Float16* __restrict__ A, const _Float16* __restrict__ Wv,
    const _Float16* __restrict__ Wg, const float* __restrict__ x,
    const float* __restrict__ gb, const int* __restrict__ mask,
    float* __restrict__ out, int M, int K, int arpb, int aR, int abase) {
  __shared__ _Float16 Al[4][2048];
  __shared__ _Float16 Bva[4][2048];
  __shared__ _Float16 Bga[4][2048];

  const int t = threadIdx.x;
  const int nbm = (M + 63) >> 6;
  const int nwg = gridDim.x;
  int bid = blockIdx.x;
  if ((nwg & 7) == 0) {
    int q = nwg >> 3;
    bid = (bid & 7) * q + (bid >> 3);
  }
  const int bm = bid % nbm, bn = bid / nbm;
  const int lane = t & 63;
  const int w = t >> 6;
  const int wm = w >> 1, wn = w & 1;

  const int r0 = t >> 2;
  const int cp = t & 3;
  const int gc = cp ^ ((r0 >> 1) & 3);
  int gr = bm * 64 + r0;  if (gr >= M) gr = M - 1;
  int ar = (gr / arpb) * aR + abase + gr % arpb;
  const int gcol = bn * 64 + r0;  // N=256 exact
  const _Float16* pA  = A + (size_t)ar * K + gc * 8;
  const _Float16* pBv = Wv + (size_t)gcol * K + gc * 8;
  const _Float16* pBg = Wg + (size_t)gcol * K + gc * 8;

#define STAGE(buf, kt)                                                         \
  do {                                                                         \
    ASYNC16(&Al[buf][t * 8], pA + (size_t)(kt) * 32);                          \
    ASYNC16(&Bva[buf][t * 8], pBv + (size_t)(kt) * 32);                        \
    ASYNC16(&Bga[buf][t * 8], pBg + (size_t)(kt) * 32);                        \
  } while (0)

  f32x4 acv[2][2], acg[2][2];
#pragma unroll
  for (int i = 0; i < 2; i++)
#pragma unroll
    for (int j = 0; j < 2; j++) {
      acv[i][j] = (f32x4){0.f, 0.f, 0.f, 0.f};
      acg[i][j] = (f32x4){0.f, 0.f, 0.f, 0.f};
    }

  const int nt = K >> 5;  // 16
  STAGE(0, 0); STAGE(1, 1); STAGE(2, 2);

  const int rl = lane & 15;
  const int ca = (lane >> 4) ^ ((rl >> 1) & 3);
  for (int kt = 0; kt < nt; ++kt) {
    if (kt < nt - 2)       asm volatile("s_waitcnt vmcnt(6)" ::: "memory");
    else if (kt == nt - 2) asm volatile("s_waitcnt vmcnt(3)" ::: "memory");
    else                   asm volatile("s_waitcnt vmcnt(0)" ::: "memory");
    __builtin_amdgcn_s_barrier();
    const int buf = kt & 3;
    half8 af[2], bv[2], bg2[2];
#pragma unroll
    for (int i = 0; i < 2; i++)
      af[i] = *(const half8*)&Al[buf][(wm * 32 + i * 16 + rl) * 32 + ca * 8];
#pragma unroll
    for (int j = 0; j < 2; j++) {
      bv[j] = *(const half8*)&Bva[buf][(wn * 32 + j * 16 + rl) * 32 + ca * 8];
      bg2[j] = *(const half8*)&Bga[buf][(wn * 32 + j * 16 + rl) * 32 + ca * 8];
    }
#pragma unroll
    for (int i = 0; i < 2; i++)
#pragma unroll
      for (int j = 0; j < 2; j++) {
        acv[i][j] = __builtin_amdgcn_mfma_f32_16x16x32_f16(af[i], bv[j],
                                                           acv[i][j], 0, 0, 0);
        acg[i][j] = __builtin_amdgcn_mfma_f32_16x16x32_f16(af[i], bg2[j],
                                                           acg[i][j], 0, 0, 0);
      }
    if (kt + 3 < nt) STAGE((kt + 3) & 3, kt + 3);
  }
#undef STAGE

  const int rb = bm * 64 + wm * 32 + ((lane >> 4) << 2);
  const int cb = bn * 64 + wn * 32 + (lane & 15);
#pragma unroll
  for (int i = 0; i < 2; i++) {
#pragma unroll
    for (int j = 0; j < 2; j++) {
      int col = cb + j * 16;
#pragma unroll
      for (int q = 0; q < 4; q++) {
        int row = rb + i * 16 + q;
        if (row >= M) continue;
        size_t idx = (size_t)row * DIN_ + col;
        float xv = x[idx];
        float res;
        if (mask[row]) {
          res = xv;
        } else {
          float gate = 1.f / (1.f + expf(-(acg[i][j][q] + gb[col])));
          res = xv + acv[i][j][q] * gate;
        }
        out[idx] = res;
      }
    }
  }
}

// ---------------------------------------------------------------------------
// LayerNorm: one block per row of 512; fp32 math, fp16 output
// ---------------------------------------------------------------------------
__global__ __launch_bounds__(256) void ln_kernel(
    const float* __restrict__ x, const float* __restrict__ g,
    const float* __restrict__ b, _Float16* __restrict__ out) {
  const int row = blockIdx.x;
  const int t = threadIdx.x;
  const float* xr = x + (size_t)row * D_;
  float v0 = xr[t], v1 = xr[t + 256];
  float s = v0 + v1, s2 = v0 * v0 + v1 * v1;
#pragma unroll
  for (int o = 32; o > 0; o >>= 1) {
    s += __shfl_down(s, o);
    s2 += __shfl_down(s2, o);
  }
  __shared__ float w1[4], w2[4], mv[2];
  const int w = t >> 6;
  if ((t & 63) == 0) { w1[w] = s; w2[w] = s2; }
  __syncthreads();
  if (t == 0) {
    float ss = w1[0] + w1[1] + w1[2] + w1[3];
    float ss2 = w2[0] + w2[1] + w2[2] + w2[3];
    float mean = ss * (1.f / D_);
    float var = ss2 * (1.f / D_) - mean * mean;
    mv[0] = mean;
    mv[1] = rsqrtf(var + 1e-5f);
  }
  __syncthreads();
  float mean = mv[0], inv = mv[1];
  _Float16* orow = out + (size_t)row * D_;
  orow[t] = (_Float16)((v0 - mean) * inv * g[t] + b[t]);
  orow[t + 256] = (_Float16)((v1 - mean) * inv * g[t + 256] + b[t + 256]);
}

// ---------------------------------------------------------------------------
// Multi-segment fp32 -> fp16 (13 segments), grid-stride over 8-elem units
// ---------------------------------------------------------------------------
struct ThSegs {
  const float* src[13];
  _Float16* dst[13];
  int cum[14];  // cumulative n8
};
__global__ void tohalf_multi_kernel(ThSegs sg) {
  int total = sg.cum[13];
  for (int i = blockIdx.x * blockDim.x + threadIdx.x; i < total;
       i += gridDim.x * blockDim.x) {
    int s = 0;
    while (i >= sg.cum[s + 1]) s++;
    int off = i - sg.cum[s];
    const float4* p = (const float4*)(sg.src[s] + (size_t)off * 8);
    float4 x = p[0], y = p[1];
    half8 h = {(_Float16)x.x, (_Float16)x.y, (_Float16)x.z, (_Float16)x.w,
               (_Float16)y.x, (_Float16)y.y, (_Float16)y.z, (_Float16)y.w};
    *(half8*)(sg.dst[s] + (size_t)off * 8) = h;
  }
}

__global__ void tohalf_kernel(const float* __restrict__ src,
                              _Float16* __restrict__ dst, int n8) {
  for (int i = blockIdx.x * blockDim.x + threadIdx.x; i < n8;
       i += gridDim.x * blockDim.x) {
    const float4* s = (const float4*)(src + (size_t)i * 8);
    float4 x = s[0], y = s[1];
    half8 h = {(_Float16)x.x, (_Float16)x.y, (_Float16)x.z, (_Float16)x.w,
               (_Float16)y.x, (_Float16)y.y, (_Float16)y.z, (_Float16)y.w};
    *(half8*)(dst + (size_t)i * 8) = h;
  }
}

// ---------------------------------------------------------------------------
// Transpose out_w (NL,512,48) -> owT (NL,48,512); writes coalesced, once/call
// ---------------------------------------------------------------------------
__global__ void transpose_ow_kernel(const float* __restrict__ out_w,
                                    float* __restrict__ owT) {
  int idx = blockIdx.x * blockDim.x + threadIdx.x;
  const int total = NL_ * 48 * D_;
  if (idx >= total) return;
  int l = idx / (48 * D_);
  int rem = idx % (48 * D_);
  int k = rem / D_;
  int c = rem % D_;
  owT[idx] = out_w[(size_t)l * D_ * 48 + (size_t)c * 48 + k];
}

// ---------------------------------------------------------------------------
// prep: concat rots/trans/mask + padded mask + zero K/V pad columns
// ---------------------------------------------------------------------------
__global__ void prep_kernel(
    const float* __restrict__ vh_rots, const float* __restrict__ vh_trans,
    const float* __restrict__ vl_rots, const float* __restrict__ vl_trans,
    const float* __restrict__ ep_rots, const float* __restrict__ ep_trans,
    const int* __restrict__ vh_mask, const int* __restrict__ vl_mask,
    const int* __restrict__ ep_mask, float* __restrict__ rots,
    float* __restrict__ trans, int* __restrict__ mask,
    int* __restrict__ maskp, float* __restrict__ Kt, float* __restrict__ PKt,
    float* __restrict__ Vt) {
  int idx = blockIdx.x * blockDim.x + threadIdx.x;
  if (idx < B_ * RP_) {
    int b = idx >> 9, r = idx & (RP_ - 1);
    if (r >= R_) {
      maskp[idx] = 1;
      return;
    }
    const float* sr; const float* st; int sm;
    if (r < VH_) {
      sr = vh_rots + (size_t)(b * VH_ + r) * 9;
      st = vh_trans + (size_t)(b * VH_ + r) * 3;
      sm = vh_mask[b * VH_ + r];
    } else if (r < VH_ + VL_) {
      int rr = r - VH_;
      sr = vl_rots + (size_t)(b * VL_ + rr) * 9;
      st = vl_trans + (size_t)(b * VL_ + rr) * 3;
      sm = vl_mask[b * VL_ + rr];
    } else {
      int rr = r - VH_ - VL_;
      sr = ep_rots + (size_t)(b * EP_ + rr) * 9;
      st = ep_trans + (size_t)(b * EP_ + rr) * 3;
      sm = ep_mask[b * EP_ + rr];
    }
    int lin = b * R_ + r;
    maskp[idx] = sm;
    mask[lin] = sm;
#pragma unroll
    for (int k = 0; k < 9; k++) rots[(size_t)lin * 9 + k] = sr[k];
#pragma unroll
    for (int k = 0; k < 3; k++) trans[(size_t)lin * 3 + k] = st[k];
  } else {
    int p = idx - B_ * RP_;
    const int per = B_ * H_ * 3 * (RP_ - R_);
    if (p >= 3 * per) return;
    int a = p / per;
    int q = p % per;
    int chan = q / (RP_ - R_), jj = q % (RP_ - R_);
    float* dst = (a == 0) ? Kt : (a == 1) ? PKt : Vt;
    dst[(size_t)chan * RP_ + R_ + jj] = 0.f;
  }
}

// ---------------------------------------------------------------------------
// Rotate QKV fields; Q-side row-major, K/V-side transposed [b][h][3][j]
// ---------------------------------------------------------------------------
__global__ __launch_bounds__(128) void rotate_kernel(
    const float* __restrict__ qkv_raw, const float* __restrict__ rots,
    const float* __restrict__ trans, float* __restrict__ Qrow,
    float* __restrict__ PQrow, float* __restrict__ Kt,
    float* __restrict__ PKt, float* __restrict__ Vt) {
  const int blk = blockIdx.x;
  const int b = blk / R_;
  const int r = blk % R_;
  const int t = threadIdx.x;
  __shared__ float Rm[9], tr[3], raw[240];
  if (t < 9) Rm[t] = rots[(size_t)blk * 9 + t];
  if (t >= 9 && t < 12) tr[t - 9] = trans[(size_t)blk * 3 + (t - 9)];
  for (int i = t; i < 240; i += 128) raw[i] = qkv_raw[(size_t)blk * 240 + i];
  __syncthreads();
  if (t < 80) {
    int f = t / 16, h = t % 16;
    float x = raw[f * 48 + h * 3 + 0];
    float y = raw[f * 48 + h * 3 + 1];
    float z = raw[f * 48 + h * 3 + 2];
    float r0 = Rm[0] * x + Rm[1] * y + Rm[2] * z;
    float r1 = Rm[3] * x + Rm[4] * y + Rm[5] * z;
    float r2 = Rm[6] * x + Rm[7] * y + Rm[8] * z;
    if (f == 2 || f == 3) { r0 += tr[0]; r1 += tr[1]; r2 += tr[2]; }
    if (f == 0 || f == 2) {
      float* dst = (f == 0) ? Qrow : PQrow;
      size_t o = (size_t)blk * 48 + h * 3;
      dst[o] = r0; dst[o + 1] = r1; dst[o + 2] = r2;
    } else {
      float* dst = (f == 1) ? Kt : (f == 3) ? PKt : Vt;
      size_t base = ((size_t)(b * H_ + h) * 3) * RP_ + r;
      dst[base] = r0; dst[base + RP_] = r1; dst[base + 2 * RP_] = r2;
    }
  }
}

// ---------------------------------------------------------------------------
// Attention: block per (b, i-pair); fused inverse-rotation + out-projection
// using TRANSPOSED weights owT[48][512] for coalesced epilogue loads.
// ---------------------------------------------------------------------------
__global__ __launch_bounds__(256) void attn2_kernel(
    const float* __restrict__ Qrow, const float* __restrict__ PQrow,
    const float* __restrict__ Kt, const float* __restrict__ PKt,
    const float* __restrict__ Vt, const float* __restrict__ rots,
    const int* __restrict__ mask, const int* __restrict__ maskp,
    const float* __restrict__ rs, const float* __restrict__ ds,
    const float* __restrict__ owT, const float* __restrict__ out_b,
    float* __restrict__ emb) {
  const int blk = blockIdx.x;
  const int b = blk / (R_ / 2);
  const int ip = blk % (R_ / 2);
  const int i0 = ip * 2;
  const int t = threadIdx.x;
  const int lane = t & 63;
  const int w = t >> 6;

  __shared__ float qs[2][48], ps[2][48], og[2][48];
  __shared__ float crs[16], cds[16];
  __shared__ int mi[2];

  if (t < 96) {
    int io = t / 48, k2 = t % 48;
    int i = i0 + io;
    qs[io][k2] = Qrow[((size_t)(b * R_ + i)) * 48 + k2];
    ps[io][k2] = PQrow[((size_t)(b * R_ + i)) * 48 + k2];
  } else if (t < 112) {
    int h = t - 96;
    const float sc = 0.57735026918962576f;
    crs[h] = log1pf(expf(rs[h])) * sc;
    cds[h] = log1pf(expf(ds[h])) * sc;
  } else if (t < 114) {
    mi[t - 112] = mask[b * R_ + i0 + (t - 112)];
  }
  __syncthreads();

  float mb[8];
#pragma unroll
  for (int jb = 0; jb < 8; jb++) {
    int j = jb * 64 + lane;
    mb[jb] = maskp[b * RP_ + j] ? -1e9f : 0.f;
  }
  const float bi0 = mi[0] ? -1e9f : 0.f;
  const float bi1 = mi[1] ? -1e9f : 0.f;

  for (int hh = 0; hh < 4; hh++) {
    const int h = hh * 4 + w;
    const float sA = crs[h], sD = cds[h];
    const float qx0 = qs[0][h * 3], qy0 = qs[0][h * 3 + 1], qz0 = qs[0][h * 3 + 2];
    const float px0 = ps[0][h * 3], py0 = ps[0][h * 3 + 1], pz0 = ps[0][h * 3 + 2];
    const float qx1 = qs[1][h * 3], qy1 = qs[1][h * 3 + 1], qz1 = qs[1][h * 3 + 2];
    const float px1 = ps[1][h * 3], py1 = ps[1][h * 3 + 1], pz1 = ps[1][h * 3 + 2];
    const float* kb = Kt + ((size_t)(b * H_ + h) * 3) * RP_;
    const float* pb = PKt + ((size_t)(b * H_ + h) * 3) * RP_;
    const float* vb = Vt + ((size_t)(b * H_ + h) * 3) * RP_;

    float l0[8], l1[8];
    float m0 = -3e38f, m1 = -3e38f;
#pragma unroll
    for (int jb = 0; jb < 8; jb++) {
      int j = jb * 64 + lane;
      float kx = kb[j], ky = kb[j + RP_], kz = kb[j + 2 * RP_];
      float pkx = pb[j], pky = pb[j + RP_], pkz = pb[j + 2 * RP_];
      float dx0 = px0 - pkx, dy0 = py0 - pky, dz0 = pz0 - pkz;
      float d0 = sqrtf(dx0 * dx0 + dy0 * dy0 + dz0 * dz0);
      l0[jb] = (qx0 * kx + qy0 * ky + qz0 * kz) * sA - d0 * sD + mb[jb] + bi0;
      m0 = fmaxf(m0, l0[jb]);
      float dx1 = px1 - pkx, dy1 = py1 - pky, dz1 = pz1 - pkz;
      float d1 = sqrtf(dx1 * dx1 + dy1 * dy1 + dz1 * dz1);
      l1[jb] = (qx1 * kx + qy1 * ky + qz1 * kz) * sA - d1 * sD + mb[jb] + bi1;
      m1 = fmaxf(m1, l1[jb]);
    }
#pragma unroll
    for (int s = 1; s < 64; s <<= 1) {
      m0 = fmaxf(m0, __shfl_xor(m0, s));
      m1 = fmaxf(m1, __shfl_xor(m1, s));
    }
    float s0 = 0.f, s1 = 0.f;
    float ox0 = 0.f, oy0 = 0.f, oz0 = 0.f, ox1 = 0.f, oy1 = 0.f, oz1 = 0.f;
#pragma unroll
    for (int jb = 0; jb < 8; jb++) {
      int j = jb * 64 + lane;
      float p0 = expf(l0[jb] - m0);
      float p1 = expf(l1[jb] - m1);
      s0 += p0; s1 += p1;
      float vx = vb[j], vy = vb[j + RP_], vz = vb[j + 2 * RP_];
      ox0 += p0 * vx; oy0 += p0 * vy; oz0 += p0 * vz;
      ox1 += p1 * vx; oy1 += p1 * vy; oz1 += p1 * vz;
    }
#pragma unroll
    for (int s = 1; s < 64; s <<= 1) {
      s0 += __shfl_xor(s0, s); s1 += __shfl_xor(s1, s);
      ox0 += __shfl_xor(ox0, s); oy0 += __shfl_xor(oy0, s); oz0 += __shfl_xor(oz0, s);
      ox1 += __shfl_xor(ox1, s); oy1 += __shfl_xor(oy1, s); oz1 += __shfl_xor(oz1, s);
    }
    if (lane == 0) {
      og[0][h * 3] = ox0 / s0; og[0][h * 3 + 1] = oy0 / s0; og[0][h * 3 + 2] = oz0 / s0;
      og[1][h * 3] = ox1 / s1; og[1][h * 3 + 1] = oy1 / s1; og[1][h * 3 + 2] = oz1 / s1;
    }
  }
  __syncthreads();
  // inverse rotation in-place on og
  float r0v0 = 0.f, r0v1 = 0.f;
  if (t < 48) {
    int h = t / 3, i3 = t % 3;
    const float* Rm0 = rots + ((size_t)(b * R_ + i0)) * 9;
    const float* Rm1 = rots + ((size_t)(b * R_ + i0 + 1)) * 9;
    r0v0 = Rm0[0 + i3] * og[0][h * 3 + 0] + Rm0[3 + i3] * og[0][h * 3 + 1] +
           Rm0[6 + i3] * og[0][h * 3 + 2];
    r0v1 = Rm1[0 + i3] * og[1][h * 3 + 0] + Rm1[3 + i3] * og[1][h * 3 + 1] +
           Rm1[6 + i3] * og[1][h * 3 + 2];
  }
  __syncthreads();
  if (t < 48) { og[0][t] = r0v0; og[1][t] = r0v1; }
  __syncthreads();
  // fused out-projection: coalesced owT[k][c] reads (c = lane-contiguous),
  // og[io][k] is a wave-uniform LDS broadcast.
#pragma unroll
  for (int io = 0; io < 2; io++) {
    float* erow = emb + ((size_t)(b * R_ + i0 + io)) * D_;
#pragma unroll
    for (int half = 0; half < 2; half++) {
      int c = half * 256 + t;
      float a0 = 0.f, a1 = 0.f, a2 = 0.f, a3 = 0.f;
#pragma unroll
      for (int k = 0; k < 48; k += 4) {
        a0 += og[io][k + 0] * owT[(size_t)(k + 0) * D_ + c];
        a1 += og[io][k + 1] * owT[(size_t)(k + 1) * D_ + c];
        a2 += og[io][k + 2] * owT[(size_t)(k + 2) * D_ + c];
        a3 += og[io][k + 3] * owT[(size_t)(k + 3) * D_ + c];
      }
      erow[c] += out_b[c] + ((a0 + a1) + (a2 + a3));
    }
  }
}

// ---------------------------------------------------------------------------
extern "C" void kernel_launch(void* const* d_in, const int* in_sizes, int n_in,
                              void* d_out, int out_size, void* d_ws, size_t ws_size,
                              hipStream_t stream) {
  const float* vh_x = (const float*)d_in[0];
  const float* vl_x = (const float*)d_in[1];
  const float* vh_rots = (const float*)d_in[2];
  const float* vh_trans = (const float*)d_in[3];
  const float* vl_rots = (const float*)d_in[4];
  const float* vl_trans = (const float*)d_in[5];
  const float* ep_feats = (const float*)d_in[6];
  const float* ep_rots = (const float*)d_in[7];
  const float* ep_trans = (const float*)d_in[8];
  const int* vh_mask = (const int*)d_in[9];
  const int* vl_mask = (const int*)d_in[10];
  const int* ep_mask = (const int*)d_in[11];
  const float* vh_emb_w = (const float*)d_in[12];
  const float* vl_emb_w = (const float*)d_in[13];
  const float* tgt_emb_w = (const float*)d_in[14];
  const float* qkv_w = (const float*)d_in[15];
  const float* out_w = (const float*)d_in[16];
  const float* out_b = (const float*)d_in[17];
  const float* ln_g = (const float*)d_in[18];
  const float* ln_b = (const float*)d_in[19];
  const float* r_scale = (const float*)d_in[20];
  const float* d_scale = (const float*)d_in[21];
  const float* ln2_g = (const float*)d_in[22];
  const float* ln2_b = (const float*)d_in[23];
  const float* w12 = (const float*)d_in[24];
  const float* w3 = (const float*)d_in[25];
  const float* out_vh_w = (const float*)d_in[26];
  const float* out_vh_gate_w = (const float*)d_in[27];
  const float* out_vh_gate_b = (const float*)d_in[28];
  const float* out_vl_w = (const float*)d_in[29];
  const float* out_vl_gate_w = (const float*)d_in[30];
  const float* out_vl_gate_b = (const float*)d_in[31];

  const int BR = B_ * R_;  // 2024

  // ---- workspace layout (256B-aligned) ----
  uint8_t* P = (uint8_t*)d_ws;
  auto alloc = [&](size_t bytes) {
    uint8_t* p = P;
    P += (bytes + 255) & ~(size_t)255;
    return p;
  };
  float* emb = (float*)alloc((size_t)BR * D_ * 4);
  _Float16* xnh = (_Float16*)alloc((size_t)BR * D_ * 2);
  float* qkvr = (float*)alloc((size_t)BR * 240 * 4);
  float* Qrow = (float*)alloc((size_t)BR * 48 * 4);
  float* PQrow = (float*)alloc((size_t)BR * 48 * 4);
  float* Kt = (float*)alloc((size_t)B_ * H_ * 3 * RP_ * 4);
  float* PKt = (float*)alloc((size_t)B_ * H_ * 3 * RP_ * 4);
  float* Vt = (float*)alloc((size_t)B_ * H_ * 3 * RP_ * 4);
  _Float16* ghalf = (_Float16*)alloc((size_t)BR * HID_ * 2);
  float* rots_c = (float*)alloc((size_t)BR * 9 * 4);
  float* trans_c = (float*)alloc((size_t)BR * 3 * 4);
  int* mask_c = (int*)alloc((size_t)BR * 4);
  int* maskp = (int*)alloc((size_t)B_ * RP_ * 4);
  float* owT = (float*)alloc((size_t)NL_ * 48 * D_ * 4);
  _Float16* embh = (_Float16*)alloc((size_t)BR * D_ * 2);
  _Float16* qkvh = (_Float16*)alloc((size_t)NL_ * 240 * D_ * 2);
  _Float16* w12h = (_Float16*)alloc((size_t)NL_ * 2 * HID_ * D_ * 2);
  _Float16* w3h = (_Float16*)alloc((size_t)NL_ * D_ * HID_ * 2);
  _Float16* vhxh = (_Float16*)alloc((size_t)B_ * VH_ * DIN_ * 2);
  _Float16* vlxh = (_Float16*)alloc((size_t)B_ * VL_ * DIN_ * 2);
  _Float16* eph = (_Float16*)alloc((size_t)B_ * EP_ * DEP_ * 2);
  _Float16* vhewh = (_Float16*)alloc((size_t)D_ * DIN_ * 2);
  _Float16* vlewh = (_Float16*)alloc((size_t)D_ * DIN_ * 2);
  _Float16* tgewh = (_Float16*)alloc((size_t)D_ * DEP_ * 2);
  _Float16* ovhw = (_Float16*)alloc((size_t)DIN_ * D_ * 2);
  _Float16* ovhgw = (_Float16*)alloc((size_t)DIN_ * D_ * 2);
  _Float16* ovlw = (_Float16*)alloc((size_t)DIN_ * D_ * 2);
  _Float16* ovlgw = (_Float16*)alloc((size_t)DIN_ * D_ * 2);

  // one multi-segment fp32->fp16 conversion (weights + inputs)
  {
    ThSegs sg;
    const float* srcs[13] = {qkv_w, w12, w3, vh_x, vl_x, ep_feats,
                             vh_emb_w, vl_emb_w, tgt_emb_w,
                             out_vh_w, out_vh_gate_w, out_vl_w, out_vl_gate_w};
    _Float16* dsts[13] = {qkvh, w12h, w3h, vhxh, vlxh, eph,
                          vhewh, vlewh, tgewh, ovhw, ovhgw, ovlw, ovlgw};
    int n8s[13] = {NL_ * 240 * D_ / 8, NL_ * 2 * HID_ * D_ / 8,
                   NL_ * D_ * HID_ / 8, B_ * VH_ * DIN_ / 8,
                   B_ * VL_ * DIN_ / 8, B_ * EP_ * DEP_ / 8,
                   D_ * DIN_ / 8, D_ * DIN_ / 8, D_ * DEP_ / 8,
                   DIN_ * D_ / 8, DIN_ * D_ / 8, DIN_ * D_ / 8, DIN_ * D_ / 8};
    int c = 0;
    for (int i = 0; i < 13; i++) {
      sg.src[i] = srcs[i]; sg.dst[i] = dsts[i];
      sg.cum[i] = c; c += n8s[i];
    }
    sg.cum[13] = c;
    tohalf_multi_kernel<<<2048, 256, 0, stream>>>(sg);
  }

  // transpose out_w for the attn epilogue (once per call)
  {
    int total = NL_ * 48 * D_;
    transpose_ow_kernel<<<(total + 255) / 256, 256, 0, stream>>>(out_w, owT);
  }

  // prep: concat + padded mask + K/V pad zero
  {
    int total = B_ * RP_ + 3 * B_ * H_ * 3 * (RP_ - R_);
    prep_kernel<<<(total + 255) / 256, 256, 0, stream>>>(
        vh_rots, vh_trans, vl_rots, vl_trans, ep_rots, ep_trans, vh_mask,
        vl_mask, ep_mask, rots_c, trans_c, mask_c, maskp, Kt, PKt, Vt);
  }

  auto gemm16b = [&](const _Float16* A, const _Float16* W, float* C,
                     const float* bias, int M, int N, int K, int mode,
                     int crpb, int cR, int cbase, int pe) {
    int nbm = (M + 63) / 64, nbn = (N + 63) / 64;
    gemm16b_kernel<<<nbm * nbn, 256, 0, stream>>>(A, W, C, bias, M, N, K, mode,
                                                  crpb, cR, cbase, pe);
  };

  // embeddings (fp16 MFMA, fused PE, remapped into emb)
  gemm16b(vhxh, vhewh, emb, nullptr, B_ * VH_, D_, DIN_, MODE_STORE,
          VH_, R_, 0, 1);
  gemm16b(vlxh, vlewh, emb, nullptr, B_ * VL_, D_, DIN_, MODE_STORE,
          VL_, R_, VH_, 1);
  gemm16b(eph, tgewh, emb, nullptr, B_ * EP_, D_, DEP_, MODE_STORE,
          EP_, R_, VH_ + VL_, 0);

  for (int l = 0; l < NL_; l++) {
    const _Float16* qwh = qkvh + (size_t)l * 240 * D_;
    const float* owTl = owT + (size_t)l * 48 * D_;
    const float* obias = out_b + (size_t)l * D_;
    const float* lg = ln_g + (size_t)l * D_;
    const float* lb = ln_b + (size_t)l * D_;
    const float* l2g = ln2_g + (size_t)l * D_;
    const float* l2b = ln2_b + (size_t)l * D_;
    const float* rs = r_scale + (size_t)l * H_;
    const float* dsc = d_scale + (size_t)l * H_;
    const _Float16* w12ah = w12h + (size_t)l * 2 * HID_ * D_;
    const _Float16* w12bh = w12ah + (size_t)HID_ * D_;
    const _Float16* w3lh = w3h + (size_t)l * D_ * HID_;

    // attention (out-projection fused into attn2, transposed weights)
    ln_kernel<<<BR, 256, 0, stream>>>(emb, lg, lb, xnh);
    gemm16b(xnh, qwh, qkvr, nullptr, BR, 240, D_, MODE_STORE, BR, BR, 0, 0);
    rotate_kernel<<<BR, 128, 0, stream>>>(qkvr, rots_c, trans_c, Qrow, PQrow,
                                          Kt, PKt, Vt);
    attn2_kernel<<<B_ * (R_ / 2), 256, 0, stream>>>(
        Qrow, PQrow, Kt, PKt, Vt, rots_c, mask_c, maskp, rs, dsc, owTl, obias,
        emb);

    // swiglu
    ln_kernel<<<BR, 256, 0, stream>>>(emb, l2g, l2b, xnh);
    {
      int nbm = (BR + 127) / 128, nbn = HID_ / 64;
      gemm16sw_kernel<<<nbm * nbn, 256, 0, stream>>>(xnh, w12ah, w12bh, ghalf,
                                                     BR, D_);
    }
    gemm16b(ghalf, w3lh, emb, nullptr, BR, D_, HID_, MODE_ADD_BIAS,
            BR, BR, 0, 0);
  }

  // output heads: emb -> fp16, then fused dual-GEMM + gate -> d_out
  tohalf_kernel<<<1024, 256, 0, stream>>>(emb, embh, BR * D_ / 8);
  {
    int M = B_ * VH_;
    int nbm = (M + 63) / 64;
    gemm16gate_kernel<<<nbm * 4, 256, 0, stream>>>(
        embh, ovhw, ovhgw, vh_x, out_vh_gate_b, vh_mask, (float*)d_out, M, D_,
        VH_, R_, 0);
  }
  {
    int M = B_ * VL_;
    int nbm = (M + 63) / 64;
    gemm16gate_kernel<<<nbm * 4, 256, 0, stream>>>(
        embh, ovlw, ovlgw, vl_x, out_vl_gate_b, vl_mask,
        (float*)d_out + (size_t)B_ * VH_ * DIN_, M, D_, VL_, R_, VH_);
  }
}